// Round 10
// baseline (633.432 us; speedup 1.0000x reference)
//
#include <hip/hip_runtime.h>

#define NN 100000
#define NE 800000
#define DD 96
#define NROWPAD 100096            // 782 * 128
#define GBLK 782                  // GEMM blocks (128 rows each)
#define SCAN_BLOCKS 100
#define SCAN_CHUNK 1000

typedef __attribute__((ext_vector_type(8))) short bf16x8;
typedef __attribute__((ext_vector_type(8))) unsigned short u16x8;
typedef __attribute__((ext_vector_type(4))) float f32x4;
typedef unsigned short u16;
typedef unsigned int u32;

#define MFMA16 __builtin_amdgcn_mfma_f32_16x16x32_bf16

// workspace layout (4-byte element offsets)
#define OFF_DEG      0u          // NN ints
#define OFF_ROWSTART 100000u     // NN+1 ints
#define OFF_CURSOR   200004u     // NN ints (becomes ORDER after fill_csr)
#define OFF_ORDER    200004u
#define OFF_BSUM     300004u     // 128 ints
#define OFF_BINS     300132u     // 128 ints (64 bins + 64 cursors)
#define OFF_STATS    300260u     // 384 floats
#define OFF_PARAMS   300644u     // 384 floats
#define OFF_WT       301028u     // 5*9216 bf16
#define OFF_CSR      324068u     // NE ints
#define OFF_XH       1124068u    // NROWPAD*96 floats (combined x|hp bf16 rows, 384B)
#define OFF_HMBF     10733284u   // NROWPAD*48 floats
#define OFF_HXBF     15537892u   // NROWPAD*48 floats

__device__ __forceinline__ u16 f2b(float f) {
  u32 u = __float_as_uint(f);
  u += 0x7FFFu + ((u >> 16) & 1u);
  return (u16)(u >> 16);
}
__device__ __forceinline__ float b2f(short h) {
  return __uint_as_float(((u32)(u16)h) << 16);
}

// ---------------- weight prep ----------------
__global__ void wprep_kernel(const float* __restrict__ Ws1, const float* __restrict__ Wn1,
                             const float* __restrict__ Ws2, const float* __restrict__ Wn2,
                             const float* __restrict__ Wp, u16* __restrict__ wt) {
  int idx = blockIdx.x * 256 + threadIdx.x;
  if (idx >= 5 * 9216) return;
  int m = idx / 9216, r = idx % 9216;
  int k = r / 96, c = r % 96;
  const float* W = (m == 0) ? Ws1 : (m == 1) ? Wn1 : (m == 2) ? Ws2 : (m == 3) ? Wn2 : Wp;
  wt[m * 9216 + c * 96 + k] = f2b(W[k * 96 + c]);
}

// ---------------- degree histogram ----------------
__global__ void deg_kernel(const int* __restrict__ dst, int* __restrict__ deg) {
  int e = blockIdx.x * blockDim.x + threadIdx.x;
  if (e >= NE) return;
  atomicAdd(&deg[dst[e]], 1);
}

// ---------------- scan phase 1 ----------------
__global__ void scan_sum_kernel(const int* __restrict__ deg, int* __restrict__ bsum) {
  __shared__ int red[256];
  int t = threadIdx.x;
  int base = blockIdx.x * SCAN_CHUNK;
  int s = 0;
  for (int i = t; i < SCAN_CHUNK; i += 256) s += deg[base + i];
  red[t] = s;
  __syncthreads();
  for (int off = 128; off > 0; off >>= 1) {
    if (t < off) red[t] += red[t + off];
    __syncthreads();
  }
  if (t == 0) bsum[blockIdx.x] = red[0];
}

// ---------------- scan phase 2 ----------------
__global__ void scan_bsum_kernel(int* __restrict__ bsum, int* __restrict__ row_start) {
  __shared__ int sm[128];
  int t = threadIdx.x;
  int v = (t < SCAN_BLOCKS) ? bsum[t] : 0;
  sm[t] = v;
  __syncthreads();
  for (int off = 1; off < 128; off <<= 1) {
    int u = 0;
    if (t >= off) u = sm[t - off];
    __syncthreads();
    if (t >= off) sm[t] += u;
    __syncthreads();
  }
  if (t < SCAN_BLOCKS) bsum[t] = sm[t] - v;
  if (t == SCAN_BLOCKS - 1) row_start[NN] = sm[t];
}

// ---------------- scan phase 3 ----------------
__global__ void scan_final_kernel(const int* __restrict__ deg,
                                  const int* __restrict__ bsum,
                                  int* __restrict__ row_start,
                                  int* __restrict__ cursor) {
  __shared__ int sm[256];
  int t = threadIdx.x;
  int base = blockIdx.x * SCAN_CHUNK + t * 4;
  int4 d = {0, 0, 0, 0};
  if (t < 250) d = *reinterpret_cast<const int4*>(deg + base);
  int tot = d.x + d.y + d.z + d.w;
  sm[t] = tot;
  __syncthreads();
  for (int off = 1; off < 256; off <<= 1) {
    int u = 0;
    if (t >= off) u = sm[t - off];
    __syncthreads();
    if (t >= off) sm[t] += u;
    __syncthreads();
  }
  if (t < 250) {
    int run = bsum[blockIdx.x] + sm[t] - tot;
    int4 rs;
    rs.x = run;
    rs.y = run + d.x;
    rs.z = run + d.x + d.y;
    rs.w = run + d.x + d.y + d.z;
    *reinterpret_cast<int4*>(row_start + base) = rs;
    *reinterpret_cast<int4*>(cursor + base) = rs;
  }
}

// ---------------- fill CSR ----------------
__global__ void fill_csr_kernel(const int* __restrict__ src,
                                const int* __restrict__ dst,
                                int* __restrict__ cursor,
                                int* __restrict__ csr) {
  int e = blockIdx.x * blockDim.x + threadIdx.x;
  if (e >= NE) return;
  int pos = atomicAdd(&cursor[dst[e]], 1);
  csr[pos] = src[e];
}

// ---------------- degree-bucket sort: hist / scan / scatter ----------------
__global__ void dhist_kernel(const int* __restrict__ deg, int* __restrict__ bins) {
  __shared__ int h[64];
  int t = threadIdx.x;
  if (t < 64) h[t] = 0;
  __syncthreads();
  int n = blockIdx.x * 256 + t;
  if (n < NN) {
    int d = deg[n]; if (d > 63) d = 63;
    atomicAdd(&h[d], 1);
  }
  __syncthreads();
  if (t < 64 && h[t]) atomicAdd(&bins[t], h[t]);
}

__global__ void bscan_kernel(const int* __restrict__ bins, int* __restrict__ bcur) {
  int t = threadIdx.x;    // 64 threads
  int v = bins[t];
  int s = v;
  for (int off = 1; off < 64; off <<= 1) {
    int u = __shfl_up(s, off);
    if (t >= off) s += u;
  }
  bcur[t] = s - v;        // exclusive prefix
}

__global__ void order_kernel(const int* __restrict__ deg, int* __restrict__ bcur,
                             int* __restrict__ order) {
  int n = blockIdx.x * 256 + threadIdx.x;
  if (n >= NN) return;
  int d = deg[n]; if (d > 63) d = 63;
  int pos = atomicAdd(&bcur[d], 1);
  order[pos] = n;
}

// ---------------- hp = relu(x @ Wp + bp) fused with x->bf16; combined xh row ----------------
__global__ __launch_bounds__(512) void hp_gemm_kernel(const float* __restrict__ x,
                                                      const u16* __restrict__ wt,
                                                      const float* __restrict__ bp,
                                                      u16* __restrict__ xh) {
  __shared__ bf16x8 wl[1152];   // Wp^T
  int t = threadIdx.x;
  const bf16x8* wg = reinterpret_cast<const bf16x8*>(wt + 4 * 9216);
  for (int j = t; j < 1152; j += 512) wl[j] = wg[j];
  __syncthreads();
  int w = t >> 6, lane = t & 63;
  int i = lane & 15, g = lane >> 4;
  int row_base = blockIdx.x * 128 + w * 16;
  int grow_a = row_base + i;
  int lrow = grow_a < NN ? grow_a : NN - 1;
  const float4* xr = reinterpret_cast<const float4*>(x + (size_t)lrow * 96);
  bf16x8* xhv = reinterpret_cast<bf16x8*>(xh);
  bf16x8 ax[3];
#pragma unroll
  for (int kb = 0; kb < 3; ++kb) {
    float4 p = xr[(kb * 4 + g) * 2];
    float4 q = xr[(kb * 4 + g) * 2 + 1];
    bf16x8 v;
    v[0] = (short)f2b(p.x); v[1] = (short)f2b(p.y); v[2] = (short)f2b(p.z); v[3] = (short)f2b(p.w);
    v[4] = (short)f2b(q.x); v[5] = (short)f2b(q.y); v[6] = (short)f2b(q.z); v[7] = (short)f2b(q.w);
    ax[kb] = v;
    xhv[(size_t)grow_a * 24 + kb * 4 + g] = v;
  }
  for (int nt = 0; nt < 6; ++nt) {
    f32x4 acc = {0.f, 0.f, 0.f, 0.f};
    int bch = (nt * 16 + i) * 12;
#pragma unroll
    for (int kb = 0; kb < 3; ++kb)
      acc = MFMA16(ax[kb], wl[bch + kb * 4 + g], acc, 0, 0, 0);
    int col = nt * 16 + i;
    float bias = bp[col];
#pragma unroll
    for (int r = 0; r < 4; ++r) {
      int grow = row_base + g * 4 + r;
      xh[(size_t)grow * 192 + 96 + col] = f2b(fmaxf(acc[r] + bias, 0.0f));
    }
  }
}

// ---------------- fused gather, degree-sorted: 32 nodes/block, 8 slots/node ----------------
__global__ __launch_bounds__(256) void gather_kernel(const u16* __restrict__ xh,
                                                     const int* __restrict__ row_start,
                                                     const int* __restrict__ csr,
                                                     const int* __restrict__ order,
                                                     u16* __restrict__ hmbf,
                                                     u16* __restrict__ hxbf) {
  int t = threadIdx.x;
  int idx = blockIdx.x * 32 + (t & 31);   // grid covers exactly NN
  int node = order[idx];
  int slot = t >> 5;            // 0..7; sum/max split at wave boundary
  bool isMax = slot >= 4;
  int beg = row_start[node], end = row_start[node + 1];
  int cbase = slot * 3;
  const u16x8* XH = reinterpret_cast<const u16x8*>(xh);
  float s0[8], s1[8], s2[8];
  u16x8 m0, m1, m2;
#pragma unroll
  for (int j = 0; j < 8; ++j) {
    s0[j] = 0.f; s1[j] = 0.f; s2[j] = 0.f;
    m0[j] = 0; m1[j] = 0; m2[j] = 0;
  }
  int e = beg;
  int i0 = csr[(e < end) ? e : 0];
  int i1 = csr[(e + 1 < end) ? e + 1 : ((end > beg) ? end - 1 : 0)];
  for (; e + 2 <= end; e += 2) {
    int p2 = e + 2, p3 = e + 3;
    int n0 = csr[(p2 < end) ? p2 : end - 1];
    int n1 = csr[(p3 < end) ? p3 : end - 1];
    size_t b0 = (size_t)i0 * 24 + cbase;
    size_t b1 = (size_t)i1 * 24 + cbase;
    u16x8 u0 = XH[b0], u1 = XH[b0 + 1], u2 = XH[b0 + 2];
    u16x8 v0 = XH[b1], v1 = XH[b1 + 1], v2 = XH[b1 + 2];
    if (isMax) {
#pragma unroll
      for (int j = 0; j < 8; ++j) {
        u16 a = u0[j] > v0[j] ? u0[j] : v0[j]; m0[j] = m0[j] > a ? m0[j] : a;
        u16 b = u1[j] > v1[j] ? u1[j] : v1[j]; m1[j] = m1[j] > b ? m1[j] : b;
        u16 c = u2[j] > v2[j] ? u2[j] : v2[j]; m2[j] = m2[j] > c ? m2[j] : c;
      }
    } else {
#pragma unroll
      for (int j = 0; j < 8; ++j) {
        s0[j] += b2f((short)u0[j]) + b2f((short)v0[j]);
        s1[j] += b2f((short)u1[j]) + b2f((short)v1[j]);
        s2[j] += b2f((short)u2[j]) + b2f((short)v2[j]);
      }
    }
    i0 = n0; i1 = n1;
  }
  if (e < end) {
    size_t b0 = (size_t)i0 * 24 + cbase;
    u16x8 u0 = XH[b0], u1 = XH[b0 + 1], u2 = XH[b0 + 2];
    if (isMax) {
#pragma unroll
      for (int j = 0; j < 8; ++j) {
        m0[j] = m0[j] > u0[j] ? m0[j] : u0[j];
        m1[j] = m1[j] > u1[j] ? m1[j] : u1[j];
        m2[j] = m2[j] > u2[j] ? m2[j] : u2[j];
      }
    } else {
#pragma unroll
      for (int j = 0; j < 8; ++j) {
        s0[j] += b2f((short)u0[j]);
        s1[j] += b2f((short)u1[j]);
        s2[j] += b2f((short)u2[j]);
      }
    }
  }
  if (isMax) {
    u16x8* dv = reinterpret_cast<u16x8*>(hxbf);
    size_t ob = (size_t)node * 12 + (slot - 4) * 3;
    dv[ob] = m0; dv[ob + 1] = m1; dv[ob + 2] = m2;
  } else {
    float scl = (end > beg) ? 1.0f / (float)(end - beg) : 0.0f;
    u16x8 w0, w1, w2;
#pragma unroll
    for (int j = 0; j < 8; ++j) {
      w0[j] = f2b(s0[j] * scl);
      w1[j] = f2b(s1[j] * scl);
      w2[j] = f2b(s2[j] * scl);
    }
    u16x8* dv = reinterpret_cast<u16x8*>(hmbf);
    size_t ob = (size_t)node * 12 + slot * 3;
    dv[ob] = w0; dv[ob + 1] = w1; dv[ob + 2] = w2;
  }
}

// ---------------- pass 1: dual GEMM -> BN stats only ----------------
__global__ __launch_bounds__(512, 4) void stats_gemm_kernel(const u16* __restrict__ xh,
                                                            const u16* __restrict__ hmbf,
                                                            const u16* __restrict__ hxbf,
                                                            const u16* __restrict__ wt,
                                                            float* __restrict__ stats) {
  __shared__ bf16x8 wl[4608];
  __shared__ float smst[384];
  int t = threadIdx.x;
  const bf16x8* wg = reinterpret_cast<const bf16x8*>(wt);
  for (int j = t; j < 4608; j += 512) wl[j] = wg[j];
  for (int j = t; j < 384; j += 512) smst[j] = 0.f;
  __syncthreads();
  int w = t >> 6, lane = t & 63;
  int i = lane & 15, g = lane >> 4;
  int row_base = blockIdx.x * 128 + w * 16;
  size_t arowx = (size_t)(row_base + i) * 24;
  size_t arowh = (size_t)(row_base + i) * 12;
  bf16x8 ax0, ax1, ax2, am0, am1, am2, ah0, ah1, ah2;
  {
    const bf16x8* X = reinterpret_cast<const bf16x8*>(xh);
    const bf16x8* M = reinterpret_cast<const bf16x8*>(hmbf);
    const bf16x8* H = reinterpret_cast<const bf16x8*>(hxbf);
    ax0 = X[arowx + g]; ax1 = X[arowx + 4 + g]; ax2 = X[arowx + 8 + g];
    am0 = M[arowh + g]; am1 = M[arowh + 4 + g]; am2 = M[arowh + 8 + g];
    ah0 = H[arowh + g]; ah1 = H[arowh + 4 + g]; ah2 = H[arowh + 8 + g];
  }
#pragma unroll
  for (int nt = 0; nt < 6; ++nt) {
    f32x4 a1 = {0.f, 0.f, 0.f, 0.f}, a2 = {0.f, 0.f, 0.f, 0.f};
    int bch = (nt * 16 + i) * 12 + g;
    a1 = MFMA16(ax0, wl[bch], a1, 0, 0, 0);
    a1 = MFMA16(ax1, wl[bch + 4], a1, 0, 0, 0);
    a1 = MFMA16(ax2, wl[bch + 8], a1, 0, 0, 0);
    a1 = MFMA16(am0, wl[1152 + bch], a1, 0, 0, 0);
    a1 = MFMA16(am1, wl[1152 + bch + 4], a1, 0, 0, 0);
    a1 = MFMA16(am2, wl[1152 + bch + 8], a1, 0, 0, 0);
    a2 = MFMA16(ax0, wl[2304 + bch], a2, 0, 0, 0);
    a2 = MFMA16(ax1, wl[2304 + bch + 4], a2, 0, 0, 0);
    a2 = MFMA16(ax2, wl[2304 + bch + 8], a2, 0, 0, 0);
    a2 = MFMA16(ah0, wl[3456 + bch], a2, 0, 0, 0);
    a2 = MFMA16(ah1, wl[3456 + bch + 4], a2, 0, 0, 0);
    a2 = MFMA16(ah2, wl[3456 + bch + 8], a2, 0, 0, 0);
    int col = nt * 16 + i;
    float s1 = 0, q1 = 0, s2 = 0, q2 = 0;
#pragma unroll
    for (int r = 0; r < 4; ++r) {
      int grow = row_base + g * 4 + r;
      if (grow < NN) {
        float v = a1[r], u = a2[r];
        s1 += v; q1 += v * v; s2 += u; q2 += u * u;
      }
    }
    s1 += __shfl_xor(s1, 16); q1 += __shfl_xor(q1, 16);
    s2 += __shfl_xor(s2, 16); q2 += __shfl_xor(q2, 16);
    s1 += __shfl_xor(s1, 32); q1 += __shfl_xor(q1, 32);
    s2 += __shfl_xor(s2, 32); q2 += __shfl_xor(q2, 32);
    if (g == 0) {
      atomicAdd(&smst[col], s1);
      atomicAdd(&smst[96 + col], q1);
      atomicAdd(&smst[192 + col], s2);
      atomicAdd(&smst[288 + col], q2);
    }
  }
  __syncthreads();
  for (int j = t; j < 384; j += 512) atomicAdd(&stats[j], smst[j]);
}

// ---------------- fold BN into per-column affine ----------------
__global__ void finalize_kernel(const float* __restrict__ stats,
                                const float* __restrict__ g1, const float* __restrict__ beta1,
                                const float* __restrict__ g2, const float* __restrict__ beta2,
                                float* __restrict__ params) {
  int c = threadIdx.x;
  if (c >= 96) return;
  const float inv_n = 1.0f / NN;
  float mu1 = stats[c] * inv_n;
  float var1 = fmaxf(stats[96 + c] * inv_n - mu1 * mu1, 0.0f);
  float is1 = rsqrtf(var1 + 1e-5f);
  float a1 = g1[c] * is1;
  params[c] = a1;
  params[96 + c] = beta1[c] - a1 * mu1;
  float mu2 = stats[192 + c] * inv_n;
  float var2 = fmaxf(stats[288 + c] * inv_n - mu2 * mu2, 0.0f);
  float is2 = rsqrtf(var2 + 1e-5f);
  float a2 = g2[c] * is2;
  params[192 + c] = a2;
  params[288 + c] = beta2[c] - a2 * mu2;
}

// ---------------- pass 2: dual GEMM recompute -> fused BN+add+leakyReLU -> out ----------------
__global__ __launch_bounds__(512, 4) void out_gemm_kernel(const u16* __restrict__ xh,
                                                          const u16* __restrict__ hmbf,
                                                          const u16* __restrict__ hxbf,
                                                          const u16* __restrict__ wt,
                                                          const float* __restrict__ params,
                                                          float* __restrict__ out) {
  __shared__ bf16x8 wl[4608];
  __shared__ float pl[384];
  int t = threadIdx.x;
  const bf16x8* wg = reinterpret_cast<const bf16x8*>(wt);
  for (int j = t; j < 4608; j += 512) wl[j] = wg[j];
  for (int j = t; j < 384; j += 512) pl[j] = params[j];
  __syncthreads();
  int w = t >> 6, lane = t & 63;
  int i = lane & 15, g = lane >> 4;
  int row_base = blockIdx.x * 128 + w * 16;
  size_t arowx = (size_t)(row_base + i) * 24;
  size_t arowh = (size_t)(row_base + i) * 12;
  bf16x8 ax0, ax1, ax2, am0, am1, am2, ah0, ah1, ah2;
  {
    const bf16x8* X = reinterpret_cast<const bf16x8*>(xh);
    const bf16x8* M = reinterpret_cast<const bf16x8*>(hmbf);
    const bf16x8* H = reinterpret_cast<const bf16x8*>(hxbf);
    ax0 = X[arowx + g]; ax1 = X[arowx + 4 + g]; ax2 = X[arowx + 8 + g];
    am0 = M[arowh + g]; am1 = M[arowh + 4 + g]; am2 = M[arowh + 8 + g];
    ah0 = H[arowh + g]; ah1 = H[arowh + 4 + g]; ah2 = H[arowh + 8 + g];
  }
#pragma unroll
  for (int nt = 0; nt < 6; ++nt) {
    f32x4 a1 = {0.f, 0.f, 0.f, 0.f}, a2 = {0.f, 0.f, 0.f, 0.f};
    int bch = (nt * 16 + i) * 12 + g;
    a1 = MFMA16(ax0, wl[bch], a1, 0, 0, 0);
    a1 = MFMA16(ax1, wl[bch + 4], a1, 0, 0, 0);
    a1 = MFMA16(ax2, wl[bch + 8], a1, 0, 0, 0);
    a1 = MFMA16(am0, wl[1152 + bch], a1, 0, 0, 0);
    a1 = MFMA16(am1, wl[1152 + bch + 4], a1, 0, 0, 0);
    a1 = MFMA16(am2, wl[1152 + bch + 8], a1, 0, 0, 0);
    a2 = MFMA16(ax0, wl[2304 + bch], a2, 0, 0, 0);
    a2 = MFMA16(ax1, wl[2304 + bch + 4], a2, 0, 0, 0);
    a2 = MFMA16(ax2, wl[2304 + bch + 8], a2, 0, 0, 0);
    a2 = MFMA16(ah0, wl[3456 + bch], a2, 0, 0, 0);
    a2 = MFMA16(ah1, wl[3456 + bch + 4], a2, 0, 0, 0);
    a2 = MFMA16(ah2, wl[3456 + bch + 8], a2, 0, 0, 0);
    int col = nt * 16 + i;
    float p1 = pl[col], c1 = pl[96 + col];
    float p2 = pl[192 + col], c2 = pl[288 + col];
#pragma unroll
    for (int r = 0; r < 4; ++r) {
      int grow = row_base + g * 4 + r;
      if (grow < NN) {
        float v = p1 * a1[r] + c1 + p2 * a2[r] + c2;
        v = v > 0.f ? v : 0.01f * v;
        out[(size_t)grow * 96 + col] = v;
      }
    }
  }
}

extern "C" void kernel_launch(void* const* d_in, const int* in_sizes, int n_in,
                              void* d_out, int out_size, void* d_ws, size_t ws_size,
                              hipStream_t stream) {
  const float* x       = (const float*)d_in[0];
  const int*   ei      = (const int*)d_in[1];
  const float* W_self1 = (const float*)d_in[2];
  const float* W_neigh1= (const float*)d_in[3];
  const float* W_pool  = (const float*)d_in[4];
  const float* b_pool  = (const float*)d_in[5];
  const float* W_self2 = (const float*)d_in[6];
  const float* W_neigh2= (const float*)d_in[7];
  const float* g1      = (const float*)d_in[8];
  const float* beta1   = (const float*)d_in[9];
  const float* g2      = (const float*)d_in[10];
  const float* beta2   = (const float*)d_in[11];
  float* out = (float*)d_out;

  float* ws = (float*)d_ws;
  int*   deg       = (int*)(ws + OFF_DEG);
  int*   row_start = (int*)(ws + OFF_ROWSTART);
  int*   cursor    = (int*)(ws + OFF_CURSOR);
  int*   order     = (int*)(ws + OFF_ORDER);   // aliases cursor (dead after fill_csr)
  int*   bsum      = (int*)(ws + OFF_BSUM);
  int*   bins      = (int*)(ws + OFF_BINS);    // 64 bins + 64 cursors
  float* stats     = ws + OFF_STATS;
  float* params    = ws + OFF_PARAMS;
  u16*   wt        = (u16*)(ws + OFF_WT);
  int*   csr       = (int*)(ws + OFF_CSR);
  u16*   xh        = (u16*)(ws + OFF_XH);
  u16*   hmbf      = (u16*)(ws + OFF_HMBF);
  u16*   hxbf      = (u16*)(ws + OFF_HXBF);

  const int* src = ei;
  const int* dst = ei + NE;

  hipMemsetAsync(deg, 0, NN * sizeof(int), stream);
  hipMemsetAsync(bins, 0, (128 + 384) * sizeof(float), stream);  // bins + stats

  wprep_kernel<<<(5 * 9216 + 255) / 256, 256, 0, stream>>>(W_self1, W_neigh1, W_self2,
                                                           W_neigh2, W_pool, wt);

  deg_kernel<<<(NE + 255) / 256, 256, 0, stream>>>(dst, deg);
  scan_sum_kernel<<<SCAN_BLOCKS, 256, 0, stream>>>(deg, bsum);
  scan_bsum_kernel<<<1, 128, 0, stream>>>(bsum, row_start);
  scan_final_kernel<<<SCAN_BLOCKS, 256, 0, stream>>>(deg, bsum, row_start, cursor);
  fill_csr_kernel<<<(NE + 255) / 256, 256, 0, stream>>>(src, dst, cursor, csr);

  // degree-bucket order (cursor region is dead now; order aliases it)
  dhist_kernel<<<(NN + 255) / 256, 256, 0, stream>>>(deg, bins);
  bscan_kernel<<<1, 64, 0, stream>>>(bins, bins + 64);
  order_kernel<<<(NN + 255) / 256, 256, 0, stream>>>(deg, bins + 64, order);

  hp_gemm_kernel<<<GBLK, 512, 0, stream>>>(x, wt, b_pool, xh);

  gather_kernel<<<(NN + 31) / 32, 256, 0, stream>>>(xh, row_start, csr, order, hmbf, hxbf);

  stats_gemm_kernel<<<GBLK, 512, 0, stream>>>(xh, hmbf, hxbf, wt, stats);
  finalize_kernel<<<1, 128, 0, stream>>>(stats, g1, beta1, g2, beta2, params);
  out_gemm_kernel<<<GBLK, 512, 0, stream>>>(xh, hmbf, hxbf, wt, params, out);
}

// Round 11
// 298.848 us; speedup vs baseline: 2.1196x; 2.1196x over previous
//
#include <hip/hip_runtime.h>

#define NN 100000
#define NE 800000
#define DD 96
#define NROWPAD 100096            // 782 * 128
#define GBLK 782                  // GEMM blocks (128 rows each)
#define SCAN_BLOCKS 100
#define SCAN_CHUNK 1000

typedef __attribute__((ext_vector_type(8))) short bf16x8;
typedef __attribute__((ext_vector_type(8))) unsigned short u16x8;
typedef __attribute__((ext_vector_type(4))) float f32x4;
typedef unsigned short u16;
typedef unsigned int u32;

#define MFMA16 __builtin_amdgcn_mfma_f32_16x16x32_bf16

// workspace layout (4-byte element offsets)
#define OFF_DEG      0u          // NN ints
#define OFF_ROWSTART 100000u     // NN+1 ints
#define OFF_CURSOR   200004u     // NN ints (becomes ORDER after fill_csr)
#define OFF_ORDER    200004u
#define OFF_BSUM     300004u     // 128 ints
#define OFF_BINS     300132u     // 2048 ints: hist[64*16] then cur[64*16], 64B padded
#define OFF_STATS    302180u     // 384 floats
#define OFF_PARAMS   302564u     // 384 floats
#define OFF_WT       302948u     // 5*9216 bf16 = 23040 floats
#define OFF_CSR      325988u     // NE ints
#define OFF_XH       1125988u    // NROWPAD*96 floats (combined x|hp bf16 rows, 384B)
#define OFF_HMBF     10735204u   // NROWPAD*48 floats
#define OFF_HXBF     15539812u   // NROWPAD*48 floats

__device__ __forceinline__ u16 f2b(float f) {
  u32 u = __float_as_uint(f);
  u += 0x7FFFu + ((u >> 16) & 1u);
  return (u16)(u >> 16);
}
__device__ __forceinline__ float b2f(short h) {
  return __uint_as_float(((u32)(u16)h) << 16);
}

// ---------------- weight prep ----------------
__global__ void wprep_kernel(const float* __restrict__ Ws1, const float* __restrict__ Wn1,
                             const float* __restrict__ Ws2, const float* __restrict__ Wn2,
                             const float* __restrict__ Wp, u16* __restrict__ wt) {
  int idx = blockIdx.x * 256 + threadIdx.x;
  if (idx >= 5 * 9216) return;
  int m = idx / 9216, r = idx % 9216;
  int k = r / 96, c = r % 96;
  const float* W = (m == 0) ? Ws1 : (m == 1) ? Wn1 : (m == 2) ? Ws2 : (m == 3) ? Wn2 : Wp;
  wt[m * 9216 + c * 96 + k] = f2b(W[k * 96 + c]);
}

// ---------------- degree histogram ----------------
__global__ void deg_kernel(const int* __restrict__ dst, int* __restrict__ deg) {
  int e = blockIdx.x * blockDim.x + threadIdx.x;
  if (e >= NE) return;
  atomicAdd(&deg[dst[e]], 1);
}

// ---------------- scan phase 1 ----------------
__global__ void scan_sum_kernel(const int* __restrict__ deg, int* __restrict__ bsum) {
  __shared__ int red[256];
  int t = threadIdx.x;
  int base = blockIdx.x * SCAN_CHUNK;
  int s = 0;
  for (int i = t; i < SCAN_CHUNK; i += 256) s += deg[base + i];
  red[t] = s;
  __syncthreads();
  for (int off = 128; off > 0; off >>= 1) {
    if (t < off) red[t] += red[t + off];
    __syncthreads();
  }
  if (t == 0) bsum[blockIdx.x] = red[0];
}

// ---------------- scan phase 2 ----------------
__global__ void scan_bsum_kernel(int* __restrict__ bsum, int* __restrict__ row_start) {
  __shared__ int sm[128];
  int t = threadIdx.x;
  int v = (t < SCAN_BLOCKS) ? bsum[t] : 0;
  sm[t] = v;
  __syncthreads();
  for (int off = 1; off < 128; off <<= 1) {
    int u = 0;
    if (t >= off) u = sm[t - off];
    __syncthreads();
    if (t >= off) sm[t] += u;
    __syncthreads();
  }
  if (t < SCAN_BLOCKS) bsum[t] = sm[t] - v;
  if (t == SCAN_BLOCKS - 1) row_start[NN] = sm[t];
}

// ---------------- scan phase 3 ----------------
__global__ void scan_final_kernel(const int* __restrict__ deg,
                                  const int* __restrict__ bsum,
                                  int* __restrict__ row_start,
                                  int* __restrict__ cursor) {
  __shared__ int sm[256];
  int t = threadIdx.x;
  int base = blockIdx.x * SCAN_CHUNK + t * 4;
  int4 d = {0, 0, 0, 0};
  if (t < 250) d = *reinterpret_cast<const int4*>(deg + base);
  int tot = d.x + d.y + d.z + d.w;
  sm[t] = tot;
  __syncthreads();
  for (int off = 1; off < 256; off <<= 1) {
    int u = 0;
    if (t >= off) u = sm[t - off];
    __syncthreads();
    if (t >= off) sm[t] += u;
    __syncthreads();
  }
  if (t < 250) {
    int run = bsum[blockIdx.x] + sm[t] - tot;
    int4 rs;
    rs.x = run;
    rs.y = run + d.x;
    rs.z = run + d.x + d.y;
    rs.w = run + d.x + d.y + d.z;
    *reinterpret_cast<int4*>(row_start + base) = rs;
    *reinterpret_cast<int4*>(cursor + base) = rs;
  }
}

// ---------------- fill CSR ----------------
__global__ void fill_csr_kernel(const int* __restrict__ src,
                                const int* __restrict__ dst,
                                int* __restrict__ cursor,
                                int* __restrict__ csr) {
  int e = blockIdx.x * blockDim.x + threadIdx.x;
  if (e >= NE) return;
  int pos = atomicAdd(&cursor[dst[e]], 1);
  csr[pos] = src[e];
}

// ---------------- degree buckets, contention-free (64B-padded bins) ----------------
__global__ void dhist_kernel(const int* __restrict__ deg, int* __restrict__ bins) {
  __shared__ int h[64];
  int t = threadIdx.x;
  if (t < 64) h[t] = 0;
  __syncthreads();
  int n = blockIdx.x * 256 + t;
  if (n < NN) {
    int d = deg[n]; if (d > 63) d = 63;
    atomicAdd(&h[d], 1);
  }
  __syncthreads();
  if (t < 64 && h[t]) atomicAdd(&bins[t * 16], h[t]);
}

__global__ void bscan_kernel(const int* __restrict__ bins, int* __restrict__ bcur) {
  int t = threadIdx.x;    // 64 threads
  int v = bins[t * 16];
  int s = v;
  for (int off = 1; off < 64; off <<= 1) {
    int u = __shfl_up(s, off);
    if (t >= off) s += u;
  }
  bcur[t * 16] = s - v;   // exclusive prefix, padded
}

// two-level: LDS-local position + one global chunk-reserve atomic per (block,bin)
__global__ void order_kernel(const int* __restrict__ deg, int* __restrict__ bcur,
                             int* __restrict__ order) {
  __shared__ int cnt[64];
  __shared__ int base[64];
  int t = threadIdx.x;
  if (t < 64) cnt[t] = 0;
  __syncthreads();
  int n = blockIdx.x * 256 + t;
  bool act = n < NN;
  int d = 0, myloc = 0;
  if (act) {
    d = deg[n]; if (d > 63) d = 63;
    myloc = atomicAdd(&cnt[d], 1);
  }
  __syncthreads();
  if (t < 64 && cnt[t] > 0) base[t] = atomicAdd(&bcur[t * 16], cnt[t]);
  __syncthreads();
  if (act) order[base[d] + myloc] = n;
}

// ---------------- hp = relu(x @ Wp + bp) fused with x->bf16; combined xh row ----------------
__global__ __launch_bounds__(512) void hp_gemm_kernel(const float* __restrict__ x,
                                                      const u16* __restrict__ wt,
                                                      const float* __restrict__ bp,
                                                      u16* __restrict__ xh) {
  __shared__ bf16x8 wl[1152];   // Wp^T
  int t = threadIdx.x;
  const bf16x8* wg = reinterpret_cast<const bf16x8*>(wt + 4 * 9216);
  for (int j = t; j < 1152; j += 512) wl[j] = wg[j];
  __syncthreads();
  int w = t >> 6, lane = t & 63;
  int i = lane & 15, g = lane >> 4;
  int row_base = blockIdx.x * 128 + w * 16;
  int grow_a = row_base + i;
  int lrow = grow_a < NN ? grow_a : NN - 1;
  const float4* xr = reinterpret_cast<const float4*>(x + (size_t)lrow * 96);
  bf16x8* xhv = reinterpret_cast<bf16x8*>(xh);
  bf16x8 ax[3];
#pragma unroll
  for (int kb = 0; kb < 3; ++kb) {
    float4 p = xr[(kb * 4 + g) * 2];
    float4 q = xr[(kb * 4 + g) * 2 + 1];
    bf16x8 v;
    v[0] = (short)f2b(p.x); v[1] = (short)f2b(p.y); v[2] = (short)f2b(p.z); v[3] = (short)f2b(p.w);
    v[4] = (short)f2b(q.x); v[5] = (short)f2b(q.y); v[6] = (short)f2b(q.z); v[7] = (short)f2b(q.w);
    ax[kb] = v;
    xhv[(size_t)grow_a * 24 + kb * 4 + g] = v;
  }
  for (int nt = 0; nt < 6; ++nt) {
    f32x4 acc = {0.f, 0.f, 0.f, 0.f};
    int bch = (nt * 16 + i) * 12;
#pragma unroll
    for (int kb = 0; kb < 3; ++kb)
      acc = MFMA16(ax[kb], wl[bch + kb * 4 + g], acc, 0, 0, 0);
    int col = nt * 16 + i;
    float bias = bp[col];
#pragma unroll
    for (int r = 0; r < 4; ++r) {
      int grow = row_base + g * 4 + r;
      xh[(size_t)grow * 192 + 96 + col] = f2b(fmaxf(acc[r] + bias, 0.0f));
    }
  }
}

// ---------------- fused gather, degree-bucketed: 32 nodes/block, 8 slots/node ----------------
__global__ __launch_bounds__(256) void gather_kernel(const u16* __restrict__ xh,
                                                     const int* __restrict__ row_start,
                                                     const int* __restrict__ csr,
                                                     const int* __restrict__ order,
                                                     u16* __restrict__ hmbf,
                                                     u16* __restrict__ hxbf) {
  int t = threadIdx.x;
  int idx = blockIdx.x * 32 + (t & 31);   // grid covers exactly NN
  int node = order[idx];
  int slot = t >> 5;            // 0..7; sum/max split at wave boundary
  bool isMax = slot >= 4;
  int beg = row_start[node], end = row_start[node + 1];
  int cbase = slot * 3;
  const u16x8* XH = reinterpret_cast<const u16x8*>(xh);
  float s0[8], s1[8], s2[8];
  u16x8 m0, m1, m2;
#pragma unroll
  for (int j = 0; j < 8; ++j) {
    s0[j] = 0.f; s1[j] = 0.f; s2[j] = 0.f;
    m0[j] = 0; m1[j] = 0; m2[j] = 0;
  }
  int e = beg;
  int i0 = csr[(e < end) ? e : 0];
  int i1 = csr[(e + 1 < end) ? e + 1 : ((end > beg) ? end - 1 : 0)];
  for (; e + 2 <= end; e += 2) {
    int p2 = e + 2, p3 = e + 3;
    int n0 = csr[(p2 < end) ? p2 : end - 1];
    int n1 = csr[(p3 < end) ? p3 : end - 1];
    size_t b0 = (size_t)i0 * 24 + cbase;
    size_t b1 = (size_t)i1 * 24 + cbase;
    u16x8 u0 = XH[b0], u1 = XH[b0 + 1], u2 = XH[b0 + 2];
    u16x8 v0 = XH[b1], v1 = XH[b1 + 1], v2 = XH[b1 + 2];
    if (isMax) {
#pragma unroll
      for (int j = 0; j < 8; ++j) {
        u16 a = u0[j] > v0[j] ? u0[j] : v0[j]; m0[j] = m0[j] > a ? m0[j] : a;
        u16 b = u1[j] > v1[j] ? u1[j] : v1[j]; m1[j] = m1[j] > b ? m1[j] : b;
        u16 c = u2[j] > v2[j] ? u2[j] : v2[j]; m2[j] = m2[j] > c ? m2[j] : c;
      }
    } else {
#pragma unroll
      for (int j = 0; j < 8; ++j) {
        s0[j] += b2f((short)u0[j]) + b2f((short)v0[j]);
        s1[j] += b2f((short)u1[j]) + b2f((short)v1[j]);
        s2[j] += b2f((short)u2[j]) + b2f((short)v2[j]);
      }
    }
    i0 = n0; i1 = n1;
  }
  if (e < end) {
    size_t b0 = (size_t)i0 * 24 + cbase;
    u16x8 u0 = XH[b0], u1 = XH[b0 + 1], u2 = XH[b0 + 2];
    if (isMax) {
#pragma unroll
      for (int j = 0; j < 8; ++j) {
        m0[j] = m0[j] > u0[j] ? m0[j] : u0[j];
        m1[j] = m1[j] > u1[j] ? m1[j] : u1[j];
        m2[j] = m2[j] > u2[j] ? m2[j] : u2[j];
      }
    } else {
#pragma unroll
      for (int j = 0; j < 8; ++j) {
        s0[j] += b2f((short)u0[j]);
        s1[j] += b2f((short)u1[j]);
        s2[j] += b2f((short)u2[j]);
      }
    }
  }
  if (isMax) {
    u16x8* dv = reinterpret_cast<u16x8*>(hxbf);
    size_t ob = (size_t)node * 12 + (slot - 4) * 3;
    dv[ob] = m0; dv[ob + 1] = m1; dv[ob + 2] = m2;
  } else {
    float scl = (end > beg) ? 1.0f / (float)(end - beg) : 0.0f;
    u16x8 w0, w1, w2;
#pragma unroll
    for (int j = 0; j < 8; ++j) {
      w0[j] = f2b(s0[j] * scl);
      w1[j] = f2b(s1[j] * scl);
      w2[j] = f2b(s2[j] * scl);
    }
    u16x8* dv = reinterpret_cast<u16x8*>(hmbf);
    size_t ob = (size_t)node * 12 + slot * 3;
    dv[ob] = w0; dv[ob + 1] = w1; dv[ob + 2] = w2;
  }
}

// ---------------- pass 1: dual GEMM -> BN stats only ----------------
__global__ __launch_bounds__(512, 4) void stats_gemm_kernel(const u16* __restrict__ xh,
                                                            const u16* __restrict__ hmbf,
                                                            const u16* __restrict__ hxbf,
                                                            const u16* __restrict__ wt,
                                                            float* __restrict__ stats) {
  __shared__ bf16x8 wl[4608];
  __shared__ float smst[384];
  int t = threadIdx.x;
  const bf16x8* wg = reinterpret_cast<const bf16x8*>(wt);
  for (int j = t; j < 4608; j += 512) wl[j] = wg[j];
  for (int j = t; j < 384; j += 512) smst[j] = 0.f;
  __syncthreads();
  int w = t >> 6, lane = t & 63;
  int i = lane & 15, g = lane >> 4;
  int row_base = blockIdx.x * 128 + w * 16;
  size_t arowx = (size_t)(row_base + i) * 24;
  size_t arowh = (size_t)(row_base + i) * 12;
  bf16x8 ax0, ax1, ax2, am0, am1, am2, ah0, ah1, ah2;
  {
    const bf16x8* X = reinterpret_cast<const bf16x8*>(xh);
    const bf16x8* M = reinterpret_cast<const bf16x8*>(hmbf);
    const bf16x8* H = reinterpret_cast<const bf16x8*>(hxbf);
    ax0 = X[arowx + g]; ax1 = X[arowx + 4 + g]; ax2 = X[arowx + 8 + g];
    am0 = M[arowh + g]; am1 = M[arowh + 4 + g]; am2 = M[arowh + 8 + g];
    ah0 = H[arowh + g]; ah1 = H[arowh + 4 + g]; ah2 = H[arowh + 8 + g];
  }
#pragma unroll
  for (int nt = 0; nt < 6; ++nt) {
    f32x4 a1 = {0.f, 0.f, 0.f, 0.f}, a2 = {0.f, 0.f, 0.f, 0.f};
    int bch = (nt * 16 + i) * 12 + g;
    a1 = MFMA16(ax0, wl[bch], a1, 0, 0, 0);
    a1 = MFMA16(ax1, wl[bch + 4], a1, 0, 0, 0);
    a1 = MFMA16(ax2, wl[bch + 8], a1, 0, 0, 0);
    a1 = MFMA16(am0, wl[1152 + bch], a1, 0, 0, 0);
    a1 = MFMA16(am1, wl[1152 + bch + 4], a1, 0, 0, 0);
    a1 = MFMA16(am2, wl[1152 + bch + 8], a1, 0, 0, 0);
    a2 = MFMA16(ax0, wl[2304 + bch], a2, 0, 0, 0);
    a2 = MFMA16(ax1, wl[2304 + bch + 4], a2, 0, 0, 0);
    a2 = MFMA16(ax2, wl[2304 + bch + 8], a2, 0, 0, 0);
    a2 = MFMA16(ah0, wl[3456 + bch], a2, 0, 0, 0);
    a2 = MFMA16(ah1, wl[3456 + bch + 4], a2, 0, 0, 0);
    a2 = MFMA16(ah2, wl[3456 + bch + 8], a2, 0, 0, 0);
    int col = nt * 16 + i;
    float s1 = 0, q1 = 0, s2 = 0, q2 = 0;
#pragma unroll
    for (int r = 0; r < 4; ++r) {
      int grow = row_base + g * 4 + r;
      if (grow < NN) {
        float v = a1[r], u = a2[r];
        s1 += v; q1 += v * v; s2 += u; q2 += u * u;
      }
    }
    s1 += __shfl_xor(s1, 16); q1 += __shfl_xor(q1, 16);
    s2 += __shfl_xor(s2, 16); q2 += __shfl_xor(q2, 16);
    s1 += __shfl_xor(s1, 32); q1 += __shfl_xor(q1, 32);
    s2 += __shfl_xor(s2, 32); q2 += __shfl_xor(q2, 32);
    if (g == 0) {
      atomicAdd(&smst[col], s1);
      atomicAdd(&smst[96 + col], q1);
      atomicAdd(&smst[192 + col], s2);
      atomicAdd(&smst[288 + col], q2);
    }
  }
  __syncthreads();
  for (int j = t; j < 384; j += 512) atomicAdd(&stats[j], smst[j]);
}

// ---------------- fold BN into per-column affine ----------------
__global__ void finalize_kernel(const float* __restrict__ stats,
                                const float* __restrict__ g1, const float* __restrict__ beta1,
                                const float* __restrict__ g2, const float* __restrict__ beta2,
                                float* __restrict__ params) {
  int c = threadIdx.x;
  if (c >= 96) return;
  const float inv_n = 1.0f / NN;
  float mu1 = stats[c] * inv_n;
  float var1 = fmaxf(stats[96 + c] * inv_n - mu1 * mu1, 0.0f);
  float is1 = rsqrtf(var1 + 1e-5f);
  float a1 = g1[c] * is1;
  params[c] = a1;
  params[96 + c] = beta1[c] - a1 * mu1;
  float mu2 = stats[192 + c] * inv_n;
  float var2 = fmaxf(stats[288 + c] * inv_n - mu2 * mu2, 0.0f);
  float is2 = rsqrtf(var2 + 1e-5f);
  float a2 = g2[c] * is2;
  params[192 + c] = a2;
  params[288 + c] = beta2[c] - a2 * mu2;
}

// ---------------- pass 2: dual GEMM recompute -> fused BN+add+leakyReLU -> out ----------------
__global__ __launch_bounds__(512, 4) void out_gemm_kernel(const u16* __restrict__ xh,
                                                          const u16* __restrict__ hmbf,
                                                          const u16* __restrict__ hxbf,
                                                          const u16* __restrict__ wt,
                                                          const float* __restrict__ params,
                                                          float* __restrict__ out) {
  __shared__ bf16x8 wl[4608];
  __shared__ float pl[384];
  int t = threadIdx.x;
  const bf16x8* wg = reinterpret_cast<const bf16x8*>(wt);
  for (int j = t; j < 4608; j += 512) wl[j] = wg[j];
  for (int j = t; j < 384; j += 512) pl[j] = params[j];
  __syncthreads();
  int w = t >> 6, lane = t & 63;
  int i = lane & 15, g = lane >> 4;
  int row_base = blockIdx.x * 128 + w * 16;
  size_t arowx = (size_t)(row_base + i) * 24;
  size_t arowh = (size_t)(row_base + i) * 12;
  bf16x8 ax0, ax1, ax2, am0, am1, am2, ah0, ah1, ah2;
  {
    const bf16x8* X = reinterpret_cast<const bf16x8*>(xh);
    const bf16x8* M = reinterpret_cast<const bf16x8*>(hmbf);
    const bf16x8* H = reinterpret_cast<const bf16x8*>(hxbf);
    ax0 = X[arowx + g]; ax1 = X[arowx + 4 + g]; ax2 = X[arowx + 8 + g];
    am0 = M[arowh + g]; am1 = M[arowh + 4 + g]; am2 = M[arowh + 8 + g];
    ah0 = H[arowh + g]; ah1 = H[arowh + 4 + g]; ah2 = H[arowh + 8 + g];
  }
#pragma unroll
  for (int nt = 0; nt < 6; ++nt) {
    f32x4 a1 = {0.f, 0.f, 0.f, 0.f}, a2 = {0.f, 0.f, 0.f, 0.f};
    int bch = (nt * 16 + i) * 12 + g;
    a1 = MFMA16(ax0, wl[bch], a1, 0, 0, 0);
    a1 = MFMA16(ax1, wl[bch + 4], a1, 0, 0, 0);
    a1 = MFMA16(ax2, wl[bch + 8], a1, 0, 0, 0);
    a1 = MFMA16(am0, wl[1152 + bch], a1, 0, 0, 0);
    a1 = MFMA16(am1, wl[1152 + bch + 4], a1, 0, 0, 0);
    a1 = MFMA16(am2, wl[1152 + bch + 8], a1, 0, 0, 0);
    a2 = MFMA16(ax0, wl[2304 + bch], a2, 0, 0, 0);
    a2 = MFMA16(ax1, wl[2304 + bch + 4], a2, 0, 0, 0);
    a2 = MFMA16(ax2, wl[2304 + bch + 8], a2, 0, 0, 0);
    a2 = MFMA16(ah0, wl[3456 + bch], a2, 0, 0, 0);
    a2 = MFMA16(ah1, wl[3456 + bch + 4], a2, 0, 0, 0);
    a2 = MFMA16(ah2, wl[3456 + bch + 8], a2, 0, 0, 0);
    int col = nt * 16 + i;
    float p1 = pl[col], c1 = pl[96 + col];
    float p2 = pl[192 + col], c2 = pl[288 + col];
#pragma unroll
    for (int r = 0; r < 4; ++r) {
      int grow = row_base + g * 4 + r;
      if (grow < NN) {
        float v = p1 * a1[r] + c1 + p2 * a2[r] + c2;
        v = v > 0.f ? v : 0.01f * v;
        out[(size_t)grow * 96 + col] = v;
      }
    }
  }
}

extern "C" void kernel_launch(void* const* d_in, const int* in_sizes, int n_in,
                              void* d_out, int out_size, void* d_ws, size_t ws_size,
                              hipStream_t stream) {
  const float* x       = (const float*)d_in[0];
  const int*   ei      = (const int*)d_in[1];
  const float* W_self1 = (const float*)d_in[2];
  const float* W_neigh1= (const float*)d_in[3];
  const float* W_pool  = (const float*)d_in[4];
  const float* b_pool  = (const float*)d_in[5];
  const float* W_self2 = (const float*)d_in[6];
  const float* W_neigh2= (const float*)d_in[7];
  const float* g1      = (const float*)d_in[8];
  const float* beta1   = (const float*)d_in[9];
  const float* g2      = (const float*)d_in[10];
  const float* beta2   = (const float*)d_in[11];
  float* out = (float*)d_out;

  float* ws = (float*)d_ws;
  int*   deg       = (int*)(ws + OFF_DEG);
  int*   row_start = (int*)(ws + OFF_ROWSTART);
  int*   cursor    = (int*)(ws + OFF_CURSOR);
  int*   order     = (int*)(ws + OFF_ORDER);   // aliases cursor (dead after fill_csr)
  int*   bsum      = (int*)(ws + OFF_BSUM);
  int*   bins      = (int*)(ws + OFF_BINS);    // hist [64*16], cur [64*16]
  float* stats     = ws + OFF_STATS;
  float* params    = ws + OFF_PARAMS;
  u16*   wt        = (u16*)(ws + OFF_WT);
  int*   csr       = (int*)(ws + OFF_CSR);
  u16*   xh        = (u16*)(ws + OFF_XH);
  u16*   hmbf      = (u16*)(ws + OFF_HMBF);
  u16*   hxbf      = (u16*)(ws + OFF_HXBF);

  const int* src = ei;
  const int* dst = ei + NE;

  hipMemsetAsync(deg, 0, NN * sizeof(int), stream);
  hipMemsetAsync(bins, 0, (2048 + 384) * sizeof(float), stream);  // bins(+cur) + stats

  wprep_kernel<<<(5 * 9216 + 255) / 256, 256, 0, stream>>>(W_self1, W_neigh1, W_self2,
                                                           W_neigh2, W_pool, wt);

  deg_kernel<<<(NE + 255) / 256, 256, 0, stream>>>(dst, deg);
  scan_sum_kernel<<<SCAN_BLOCKS, 256, 0, stream>>>(deg, bsum);
  scan_bsum_kernel<<<1, 128, 0, stream>>>(bsum, row_start);
  scan_final_kernel<<<SCAN_BLOCKS, 256, 0, stream>>>(deg, bsum, row_start, cursor);
  fill_csr_kernel<<<(NE + 255) / 256, 256, 0, stream>>>(src, dst, cursor, csr);

  // degree buckets (contention-free)
  dhist_kernel<<<(NN + 255) / 256, 256, 0, stream>>>(deg, bins);
  bscan_kernel<<<1, 64, 0, stream>>>(bins, bins + 1024);
  order_kernel<<<(NN + 255) / 256, 256, 0, stream>>>(deg, bins + 1024, order);

  hp_gemm_kernel<<<GBLK, 512, 0, stream>>>(x, wt, b_pool, xh);

  gather_kernel<<<(NN + 31) / 32, 256, 0, stream>>>(xh, row_start, csr, order, hmbf, hxbf);

  stats_gemm_kernel<<<GBLK, 512, 0, stream>>>(xh, hmbf, hxbf, wt, stats);
  finalize_kernel<<<1, 128, 0, stream>>>(stats, g1, beta1, g2, beta2, params);
  out_gemm_kernel<<<GBLK, 512, 0, stream>>>(xh, hmbf, hxbf, wt, params, out);
}

// Round 12
// 267.950 us; speedup vs baseline: 2.3640x; 1.1153x over previous
//
#include <hip/hip_runtime.h>

#define NN 100000
#define NE 800000
#define DD 96
#define NROWPAD 100096            // 782 * 128
#define GBLK 782                  // GEMM blocks (128 rows each)
#define SCAN_BLOCKS 100
#define SCAN_CHUNK 1000

typedef __attribute__((ext_vector_type(8))) short bf16x8;
typedef __attribute__((ext_vector_type(8))) unsigned short u16x8;
typedef __attribute__((ext_vector_type(4))) float f32x4;
typedef unsigned short u16;
typedef unsigned int u32;

#define MFMA16 __builtin_amdgcn_mfma_f32_16x16x32_bf16

// workspace layout (4-byte element offsets)
#define OFF_DEG      0u          // NN ints
#define OFF_ROWSTART 100000u     // NN+1 ints
#define OFF_CURSOR   200004u     // NN ints
#define OFF_BSUM     300004u     // 128 ints
#define OFF_STATS    302180u     // 384 floats
#define OFF_PARAMS   302564u     // 384 floats
#define OFF_WT       302948u     // 5*9216 bf16 = 23040 floats
#define OFF_CSR      325988u     // NE ints
#define OFF_XH       1125988u    // NROWPAD*96 floats (combined x|hp bf16 rows, 384B)
#define OFF_HMBF     10735204u   // NROWPAD*48 floats
#define OFF_HXBF     15539812u   // NROWPAD*48 floats

__device__ __forceinline__ u16 f2b(float f) {
  u32 u = __float_as_uint(f);
  u += 0x7FFFu + ((u >> 16) & 1u);
  return (u16)(u >> 16);
}
__device__ __forceinline__ float b2f(short h) {
  return __uint_as_float(((u32)(u16)h) << 16);
}

// ---------------- weight prep ----------------
__global__ void wprep_kernel(const float* __restrict__ Ws1, const float* __restrict__ Wn1,
                             const float* __restrict__ Ws2, const float* __restrict__ Wn2,
                             const float* __restrict__ Wp, u16* __restrict__ wt) {
  int idx = blockIdx.x * 256 + threadIdx.x;
  if (idx >= 5 * 9216) return;
  int m = idx / 9216, r = idx % 9216;
  int k = r / 96, c = r % 96;
  const float* W = (m == 0) ? Ws1 : (m == 1) ? Wn1 : (m == 2) ? Ws2 : (m == 3) ? Wn2 : Wp;
  wt[m * 9216 + c * 96 + k] = f2b(W[k * 96 + c]);
}

// ---------------- degree histogram ----------------
__global__ void deg_kernel(const int* __restrict__ dst, int* __restrict__ deg) {
  int e = blockIdx.x * blockDim.x + threadIdx.x;
  if (e >= NE) return;
  atomicAdd(&deg[dst[e]], 1);
}

// ---------------- scan phase 1 ----------------
__global__ void scan_sum_kernel(const int* __restrict__ deg, int* __restrict__ bsum) {
  __shared__ int red[256];
  int t = threadIdx.x;
  int base = blockIdx.x * SCAN_CHUNK;
  int s = 0;
  for (int i = t; i < SCAN_CHUNK; i += 256) s += deg[base + i];
  red[t] = s;
  __syncthreads();
  for (int off = 128; off > 0; off >>= 1) {
    if (t < off) red[t] += red[t + off];
    __syncthreads();
  }
  if (t == 0) bsum[blockIdx.x] = red[0];
}

// ---------------- scan phase 2 ----------------
__global__ void scan_bsum_kernel(int* __restrict__ bsum, int* __restrict__ row_start) {
  __shared__ int sm[128];
  int t = threadIdx.x;
  int v = (t < SCAN_BLOCKS) ? bsum[t] : 0;
  sm[t] = v;
  __syncthreads();
  for (int off = 1; off < 128; off <<= 1) {
    int u = 0;
    if (t >= off) u = sm[t - off];
    __syncthreads();
    if (t >= off) sm[t] += u;
    __syncthreads();
  }
  if (t < SCAN_BLOCKS) bsum[t] = sm[t] - v;
  if (t == SCAN_BLOCKS - 1) row_start[NN] = sm[t];
}

// ---------------- scan phase 3 ----------------
__global__ void scan_final_kernel(const int* __restrict__ deg,
                                  const int* __restrict__ bsum,
                                  int* __restrict__ row_start,
                                  int* __restrict__ cursor) {
  __shared__ int sm[256];
  int t = threadIdx.x;
  int base = blockIdx.x * SCAN_CHUNK + t * 4;
  int4 d = {0, 0, 0, 0};
  if (t < 250) d = *reinterpret_cast<const int4*>(deg + base);
  int tot = d.x + d.y + d.z + d.w;
  sm[t] = tot;
  __syncthreads();
  for (int off = 1; off < 256; off <<= 1) {
    int u = 0;
    if (t >= off) u = sm[t - off];
    __syncthreads();
    if (t >= off) sm[t] += u;
    __syncthreads();
  }
  if (t < 250) {
    int run = bsum[blockIdx.x] + sm[t] - tot;
    int4 rs;
    rs.x = run;
    rs.y = run + d.x;
    rs.z = run + d.x + d.y;
    rs.w = run + d.x + d.y + d.z;
    *reinterpret_cast<int4*>(row_start + base) = rs;
    *reinterpret_cast<int4*>(cursor + base) = rs;
  }
}

// ---------------- fill CSR ----------------
__global__ void fill_csr_kernel(const int* __restrict__ src,
                                const int* __restrict__ dst,
                                int* __restrict__ cursor,
                                int* __restrict__ csr) {
  int e = blockIdx.x * blockDim.x + threadIdx.x;
  if (e >= NE) return;
  int pos = atomicAdd(&cursor[dst[e]], 1);
  csr[pos] = src[e];
}

// ---------------- hp = relu(x @ Wp + bp) fused with x->bf16; combined xh row ----------------
__global__ __launch_bounds__(512) void hp_gemm_kernel(const float* __restrict__ x,
                                                      const u16* __restrict__ wt,
                                                      const float* __restrict__ bp,
                                                      u16* __restrict__ xh) {
  __shared__ bf16x8 wl[1152];   // Wp^T
  int t = threadIdx.x;
  const bf16x8* wg = reinterpret_cast<const bf16x8*>(wt + 4 * 9216);
  for (int j = t; j < 1152; j += 512) wl[j] = wg[j];
  __syncthreads();
  int w = t >> 6, lane = t & 63;
  int i = lane & 15, g = lane >> 4;
  int row_base = blockIdx.x * 128 + w * 16;
  int grow_a = row_base + i;
  int lrow = grow_a < NN ? grow_a : NN - 1;
  const float4* xr = reinterpret_cast<const float4*>(x + (size_t)lrow * 96);
  bf16x8* xhv = reinterpret_cast<bf16x8*>(xh);
  bf16x8 ax[3];
#pragma unroll
  for (int kb = 0; kb < 3; ++kb) {
    float4 p = xr[(kb * 4 + g) * 2];
    float4 q = xr[(kb * 4 + g) * 2 + 1];
    bf16x8 v;
    v[0] = (short)f2b(p.x); v[1] = (short)f2b(p.y); v[2] = (short)f2b(p.z); v[3] = (short)f2b(p.w);
    v[4] = (short)f2b(q.x); v[5] = (short)f2b(q.y); v[6] = (short)f2b(q.z); v[7] = (short)f2b(q.w);
    ax[kb] = v;
    xhv[(size_t)grow_a * 24 + kb * 4 + g] = v;
  }
  for (int nt = 0; nt < 6; ++nt) {
    f32x4 acc = {0.f, 0.f, 0.f, 0.f};
    int bch = (nt * 16 + i) * 12;
#pragma unroll
    for (int kb = 0; kb < 3; ++kb)
      acc = MFMA16(ax[kb], wl[bch + kb * 4 + g], acc, 0, 0, 0);
    int col = nt * 16 + i;
    float bias = bp[col];
#pragma unroll
    for (int r = 0; r < 4; ++r) {
      int grow = row_base + g * 4 + r;
      xh[(size_t)grow * 192 + 96 + col] = f2b(fmaxf(acc[r] + bias, 0.0f));
    }
  }
}

// ---------------- fused gather (natural order): 32 nodes/block, 8 slots/node ----------------
__global__ __launch_bounds__(256) void gather_kernel(const u16* __restrict__ xh,
                                                     const int* __restrict__ row_start,
                                                     const int* __restrict__ csr,
                                                     u16* __restrict__ hmbf,
                                                     u16* __restrict__ hxbf) {
  int t = threadIdx.x;
  int node = blockIdx.x * 32 + (t & 31);
  int slot = t >> 5;            // 0..7; sum/max split at wave boundary
  bool isMax = slot >= 4;
  if (node >= NN) return;
  int beg = row_start[node], end = row_start[node + 1];
  int cbase = slot * 3;
  const u16x8* XH = reinterpret_cast<const u16x8*>(xh);
  float s0[8], s1[8], s2[8];
  u16x8 m0, m1, m2;
#pragma unroll
  for (int j = 0; j < 8; ++j) {
    s0[j] = 0.f; s1[j] = 0.f; s2[j] = 0.f;
    m0[j] = 0; m1[j] = 0; m2[j] = 0;
  }
  int e = beg;
  int i0 = csr[(e < end) ? e : 0];
  int i1 = csr[(e + 1 < end) ? e + 1 : ((end > beg) ? end - 1 : 0)];
  for (; e + 2 <= end; e += 2) {
    int p2 = e + 2, p3 = e + 3;
    int n0 = csr[(p2 < end) ? p2 : end - 1];
    int n1 = csr[(p3 < end) ? p3 : end - 1];
    size_t b0 = (size_t)i0 * 24 + cbase;
    size_t b1 = (size_t)i1 * 24 + cbase;
    u16x8 u0 = XH[b0], u1 = XH[b0 + 1], u2 = XH[b0 + 2];
    u16x8 v0 = XH[b1], v1 = XH[b1 + 1], v2 = XH[b1 + 2];
    if (isMax) {
#pragma unroll
      for (int j = 0; j < 8; ++j) {
        u16 a = u0[j] > v0[j] ? u0[j] : v0[j]; m0[j] = m0[j] > a ? m0[j] : a;
        u16 b = u1[j] > v1[j] ? u1[j] : v1[j]; m1[j] = m1[j] > b ? m1[j] : b;
        u16 c = u2[j] > v2[j] ? u2[j] : v2[j]; m2[j] = m2[j] > c ? m2[j] : c;
      }
    } else {
#pragma unroll
      for (int j = 0; j < 8; ++j) {
        s0[j] += b2f((short)u0[j]) + b2f((short)v0[j]);
        s1[j] += b2f((short)u1[j]) + b2f((short)v1[j]);
        s2[j] += b2f((short)u2[j]) + b2f((short)v2[j]);
      }
    }
    i0 = n0; i1 = n1;
  }
  if (e < end) {
    size_t b0 = (size_t)i0 * 24 + cbase;
    u16x8 u0 = XH[b0], u1 = XH[b0 + 1], u2 = XH[b0 + 2];
    if (isMax) {
#pragma unroll
      for (int j = 0; j < 8; ++j) {
        m0[j] = m0[j] > u0[j] ? m0[j] : u0[j];
        m1[j] = m1[j] > u1[j] ? m1[j] : u1[j];
        m2[j] = m2[j] > u2[j] ? m2[j] : u2[j];
      }
    } else {
#pragma unroll
      for (int j = 0; j < 8; ++j) {
        s0[j] += b2f((short)u0[j]);
        s1[j] += b2f((short)u1[j]);
        s2[j] += b2f((short)u2[j]);
      }
    }
  }
  if (isMax) {
    u16x8* dv = reinterpret_cast<u16x8*>(hxbf);
    size_t ob = (size_t)node * 12 + (slot - 4) * 3;
    dv[ob] = m0; dv[ob + 1] = m1; dv[ob + 2] = m2;
  } else {
    float scl = (end > beg) ? 1.0f / (float)(end - beg) : 0.0f;
    u16x8 w0, w1, w2;
#pragma unroll
    for (int j = 0; j < 8; ++j) {
      w0[j] = f2b(s0[j] * scl);
      w1[j] = f2b(s1[j] * scl);
      w2[j] = f2b(s2[j] * scl);
    }
    u16x8* dv = reinterpret_cast<u16x8*>(hmbf);
    size_t ob = (size_t)node * 12 + slot * 3;
    dv[ob] = w0; dv[ob + 1] = w1; dv[ob + 2] = w2;
  }
}

// ---------------- pass 1: dual GEMM -> BN stats, split into two LDS phases ----------------
__global__ __launch_bounds__(512, 6) void stats_gemm_kernel(const u16* __restrict__ xh,
                                                            const u16* __restrict__ hmbf,
                                                            const u16* __restrict__ hxbf,
                                                            const u16* __restrict__ wt,
                                                            float* __restrict__ stats) {
  __shared__ bf16x8 wl[2304];   // two matrices at a time
  __shared__ float smst[384];
  int t = threadIdx.x;
  const bf16x8* wg = reinterpret_cast<const bf16x8*>(wt);
  for (int j = t; j < 2304; j += 512) wl[j] = wg[j];          // Ws1, Wn1
  for (int j = t; j < 384; j += 512) smst[j] = 0.f;
  __syncthreads();
  int w = t >> 6, lane = t & 63;
  int i = lane & 15, g = lane >> 4;
  int row_base = blockIdx.x * 128 + w * 16;
  size_t arowx = (size_t)(row_base + i) * 24;
  size_t arowh = (size_t)(row_base + i) * 12;
  const bf16x8* X = reinterpret_cast<const bf16x8*>(xh);
  const bf16x8* M = reinterpret_cast<const bf16x8*>(hmbf);
  const bf16x8* H = reinterpret_cast<const bf16x8*>(hxbf);
  bf16x8 ax0 = X[arowx + g], ax1 = X[arowx + 4 + g], ax2 = X[arowx + 8 + g];
  {
    bf16x8 am0 = M[arowh + g], am1 = M[arowh + 4 + g], am2 = M[arowh + 8 + g];
#pragma unroll
    for (int nt = 0; nt < 6; ++nt) {
      f32x4 a1 = {0.f, 0.f, 0.f, 0.f};
      int bch = (nt * 16 + i) * 12 + g;
      a1 = MFMA16(ax0, wl[bch], a1, 0, 0, 0);
      a1 = MFMA16(ax1, wl[bch + 4], a1, 0, 0, 0);
      a1 = MFMA16(ax2, wl[bch + 8], a1, 0, 0, 0);
      a1 = MFMA16(am0, wl[1152 + bch], a1, 0, 0, 0);
      a1 = MFMA16(am1, wl[1152 + bch + 4], a1, 0, 0, 0);
      a1 = MFMA16(am2, wl[1152 + bch + 8], a1, 0, 0, 0);
      int col = nt * 16 + i;
      float s1 = 0, q1 = 0;
#pragma unroll
      for (int r = 0; r < 4; ++r) {
        int grow = row_base + g * 4 + r;
        if (grow < NN) { float v = a1[r]; s1 += v; q1 += v * v; }
      }
      s1 += __shfl_xor(s1, 16); q1 += __shfl_xor(q1, 16);
      s1 += __shfl_xor(s1, 32); q1 += __shfl_xor(q1, 32);
      if (g == 0) {
        atomicAdd(&smst[col], s1);
        atomicAdd(&smst[96 + col], q1);
      }
    }
  }
  __syncthreads();
  for (int j = t; j < 2304; j += 512) wl[j] = wg[2304 + j];   // Ws2, Wn2
  __syncthreads();
  {
    bf16x8 ah0 = H[arowh + g], ah1 = H[arowh + 4 + g], ah2 = H[arowh + 8 + g];
#pragma unroll
    for (int nt = 0; nt < 6; ++nt) {
      f32x4 a2 = {0.f, 0.f, 0.f, 0.f};
      int bch = (nt * 16 + i) * 12 + g;
      a2 = MFMA16(ax0, wl[bch], a2, 0, 0, 0);
      a2 = MFMA16(ax1, wl[bch + 4], a2, 0, 0, 0);
      a2 = MFMA16(ax2, wl[bch + 8], a2, 0, 0, 0);
      a2 = MFMA16(ah0, wl[1152 + bch], a2, 0, 0, 0);
      a2 = MFMA16(ah1, wl[1152 + bch + 4], a2, 0, 0, 0);
      a2 = MFMA16(ah2, wl[1152 + bch + 8], a2, 0, 0, 0);
      int col = nt * 16 + i;
      float s2 = 0, q2 = 0;
#pragma unroll
      for (int r = 0; r < 4; ++r) {
        int grow = row_base + g * 4 + r;
        if (grow < NN) { float v = a2[r]; s2 += v; q2 += v * v; }
      }
      s2 += __shfl_xor(s2, 16); q2 += __shfl_xor(q2, 16);
      s2 += __shfl_xor(s2, 32); q2 += __shfl_xor(q2, 32);
      if (g == 0) {
        atomicAdd(&smst[192 + col], s2);
        atomicAdd(&smst[288 + col], q2);
      }
    }
  }
  __syncthreads();
  for (int j = t; j < 384; j += 512) atomicAdd(&stats[j], smst[j]);
}

// ---------------- fold BN into per-column affine ----------------
__global__ void finalize_kernel(const float* __restrict__ stats,
                                const float* __restrict__ g1, const float* __restrict__ beta1,
                                const float* __restrict__ g2, const float* __restrict__ beta2,
                                float* __restrict__ params) {
  int c = threadIdx.x;
  if (c >= 96) return;
  const float inv_n = 1.0f / NN;
  float mu1 = stats[c] * inv_n;
  float var1 = fmaxf(stats[96 + c] * inv_n - mu1 * mu1, 0.0f);
  float is1 = rsqrtf(var1 + 1e-5f);
  float a1 = g1[c] * is1;
  params[c] = a1;
  params[96 + c] = beta1[c] - a1 * mu1;
  float mu2 = stats[192 + c] * inv_n;
  float var2 = fmaxf(stats[288 + c] * inv_n - mu2 * mu2, 0.0f);
  float is2 = rsqrtf(var2 + 1e-5f);
  float a2 = g2[c] * is2;
  params[192 + c] = a2;
  params[288 + c] = beta2[c] - a2 * mu2;
}

// ---------------- pass 2: dual GEMM recompute -> fused output, split LDS phases ----------------
__global__ __launch_bounds__(512, 4) void out_gemm_kernel(const u16* __restrict__ xh,
                                                          const u16* __restrict__ hmbf,
                                                          const u16* __restrict__ hxbf,
                                                          const u16* __restrict__ wt,
                                                          const float* __restrict__ params,
                                                          float* __restrict__ out) {
  __shared__ bf16x8 wl[2304];
  __shared__ float pl[384];
  int t = threadIdx.x;
  const bf16x8* wg = reinterpret_cast<const bf16x8*>(wt);
  for (int j = t; j < 2304; j += 512) wl[j] = wg[j];          // Ws1, Wn1
  for (int j = t; j < 384; j += 512) pl[j] = params[j];
  __syncthreads();
  int w = t >> 6, lane = t & 63;
  int i = lane & 15, g = lane >> 4;
  int row_base = blockIdx.x * 128 + w * 16;
  size_t arowx = (size_t)(row_base + i) * 24;
  size_t arowh = (size_t)(row_base + i) * 12;
  const bf16x8* X = reinterpret_cast<const bf16x8*>(xh);
  const bf16x8* M = reinterpret_cast<const bf16x8*>(hmbf);
  const bf16x8* H = reinterpret_cast<const bf16x8*>(hxbf);
  bf16x8 ax0 = X[arowx + g], ax1 = X[arowx + 4 + g], ax2 = X[arowx + 8 + g];
  f32x4 o1[6];
  {
    bf16x8 am0 = M[arowh + g], am1 = M[arowh + 4 + g], am2 = M[arowh + 8 + g];
#pragma unroll
    for (int nt = 0; nt < 6; ++nt) {
      f32x4 a1 = {0.f, 0.f, 0.f, 0.f};
      int bch = (nt * 16 + i) * 12 + g;
      a1 = MFMA16(ax0, wl[bch], a1, 0, 0, 0);
      a1 = MFMA16(ax1, wl[bch + 4], a1, 0, 0, 0);
      a1 = MFMA16(ax2, wl[bch + 8], a1, 0, 0, 0);
      a1 = MFMA16(am0, wl[1152 + bch], a1, 0, 0, 0);
      a1 = MFMA16(am1, wl[1152 + bch + 4], a1, 0, 0, 0);
      a1 = MFMA16(am2, wl[1152 + bch + 8], a1, 0, 0, 0);
      o1[nt] = a1;
    }
  }
  __syncthreads();
  for (int j = t; j < 2304; j += 512) wl[j] = wg[2304 + j];   // Ws2, Wn2
  __syncthreads();
  {
    bf16x8 ah0 = H[arowh + g], ah1 = H[arowh + 4 + g], ah2 = H[arowh + 8 + g];
#pragma unroll
    for (int nt = 0; nt < 6; ++nt) {
      f32x4 a2 = {0.f, 0.f, 0.f, 0.f};
      int bch = (nt * 16 + i) * 12 + g;
      a2 = MFMA16(ax0, wl[bch], a2, 0, 0, 0);
      a2 = MFMA16(ax1, wl[bch + 4], a2, 0, 0, 0);
      a2 = MFMA16(ax2, wl[bch + 8], a2, 0, 0, 0);
      a2 = MFMA16(ah0, wl[1152 + bch], a2, 0, 0, 0);
      a2 = MFMA16(ah1, wl[1152 + bch + 4], a2, 0, 0, 0);
      a2 = MFMA16(ah2, wl[1152 + bch + 8], a2, 0, 0, 0);
      int col = nt * 16 + i;
      float p1 = pl[col], c1 = pl[96 + col];
      float p2 = pl[192 + col], c2 = pl[288 + col];
#pragma unroll
      for (int r = 0; r < 4; ++r) {
        int grow = row_base + g * 4 + r;
        if (grow < NN) {
          float v = p1 * o1[nt][r] + c1 + p2 * a2[r] + c2;
          v = v > 0.f ? v : 0.01f * v;
          out[(size_t)grow * 96 + col] = v;
        }
      }
    }
  }
}

extern "C" void kernel_launch(void* const* d_in, const int* in_sizes, int n_in,
                              void* d_out, int out_size, void* d_ws, size_t ws_size,
                              hipStream_t stream) {
  const float* x       = (const float*)d_in[0];
  const int*   ei      = (const int*)d_in[1];
  const float* W_self1 = (const float*)d_in[2];
  const float* W_neigh1= (const float*)d_in[3];
  const float* W_pool  = (const float*)d_in[4];
  const float* b_pool  = (const float*)d_in[5];
  const float* W_self2 = (const float*)d_in[6];
  const float* W_neigh2= (const float*)d_in[7];
  const float* g1      = (const float*)d_in[8];
  const float* beta1   = (const float*)d_in[9];
  const float* g2      = (const float*)d_in[10];
  const float* beta2   = (const float*)d_in[11];
  float* out = (float*)d_out;

  float* ws = (float*)d_ws;
  int*   deg       = (int*)(ws + OFF_DEG);
  int*   row_start = (int*)(ws + OFF_ROWSTART);
  int*   cursor    = (int*)(ws + OFF_CURSOR);
  int*   bsum      = (int*)(ws + OFF_BSUM);
  float* stats     = ws + OFF_STATS;
  float* params    = ws + OFF_PARAMS;
  u16*   wt        = (u16*)(ws + OFF_WT);
  int*   csr       = (int*)(ws + OFF_CSR);
  u16*   xh        = (u16*)(ws + OFF_XH);
  u16*   hmbf      = (u16*)(ws + OFF_HMBF);
  u16*   hxbf      = (u16*)(ws + OFF_HXBF);

  const int* src = ei;
  const int* dst = ei + NE;

  hipMemsetAsync(deg, 0, NN * sizeof(int), stream);
  hipMemsetAsync(stats, 0, 384 * sizeof(float), stream);

  wprep_kernel<<<(5 * 9216 + 255) / 256, 256, 0, stream>>>(W_self1, W_neigh1, W_self2,
                                                           W_neigh2, W_pool, wt);

  deg_kernel<<<(NE + 255) / 256, 256, 0, stream>>>(dst, deg);
  scan_sum_kernel<<<SCAN_BLOCKS, 256, 0, stream>>>(deg, bsum);
  scan_bsum_kernel<<<1, 128, 0, stream>>>(bsum, row_start);
  scan_final_kernel<<<SCAN_BLOCKS, 256, 0, stream>>>(deg, bsum, row_start, cursor);
  fill_csr_kernel<<<(NE + 255) / 256, 256, 0, stream>>>(src, dst, cursor, csr);

  hp_gemm_kernel<<<GBLK, 512, 0, stream>>>(x, wt, b_pool, xh);

  gather_kernel<<<(NN + 31) / 32, 256, 0, stream>>>(xh, row_start, csr, hmbf, hxbf);

  stats_gemm_kernel<<<GBLK, 512, 0, stream>>>(xh, hmbf, hxbf, wt, stats);
  finalize_kernel<<<1, 128, 0, stream>>>(stats, g1, beta1, g2, beta2, params);
  out_gemm_kernel<<<GBLK, 512, 0, stream>>>(xh, hmbf, hxbf, wt, params, out);
}

// Round 13
// 262.575 us; speedup vs baseline: 2.4124x; 1.0205x over previous
//
#include <hip/hip_runtime.h>

#define NN 100000
#define NE 800000
#define DD 96
#define NROWPAD 100096            // 782 * 128
#define GBLK 782                  // GEMM blocks (128 rows each)
#define SCAN_BLOCKS 100
#define SCAN_CHUNK 1000

typedef __attribute__((ext_vector_type(8))) short bf16x8;
typedef __attribute__((ext_vector_type(8))) unsigned short u16x8;
typedef __attribute__((ext_vector_type(4))) float f32x4;
typedef unsigned short u16;
typedef unsigned int u32;

#define MFMA16 __builtin_amdgcn_mfma_f32_16x16x32_bf16

// workspace layout (4-byte element offsets)
#define OFF_DEG      0u          // NN ints
#define OFF_ROWSTART 100000u     // NN+1 ints
#define OFF_CURSOR   200004u     // NN ints
#define OFF_BSUM     300004u     // 128 ints
#define OFF_STATS    302180u     // 384 floats
#define OFF_WT       302948u     // 5*9216 bf16 = 23040 floats
#define OFF_CSR      325988u     // NE ints
#define OFF_XH       1125988u    // NROWPAD*96 floats (combined x|hp bf16 rows, 384B)
#define OFF_HMBF     10735204u   // NROWPAD*48 floats
#define OFF_HXBF     15539812u   // NROWPAD*48 floats

__device__ __forceinline__ u16 f2b(float f) {
  u32 u = __float_as_uint(f);
  u += 0x7FFFu + ((u >> 16) & 1u);
  return (u16)(u >> 16);
}
__device__ __forceinline__ float b2f(short h) {
  return __uint_as_float(((u32)(u16)h) << 16);
}

// ---------------- weight prep ----------------
__global__ void wprep_kernel(const float* __restrict__ Ws1, const float* __restrict__ Wn1,
                             const float* __restrict__ Ws2, const float* __restrict__ Wn2,
                             const float* __restrict__ Wp, u16* __restrict__ wt) {
  int idx = blockIdx.x * 256 + threadIdx.x;
  if (idx >= 5 * 9216) return;
  int m = idx / 9216, r = idx % 9216;
  int k = r / 96, c = r % 96;
  const float* W = (m == 0) ? Ws1 : (m == 1) ? Wn1 : (m == 2) ? Ws2 : (m == 3) ? Wn2 : Wp;
  wt[m * 9216 + c * 96 + k] = f2b(W[k * 96 + c]);
}

// ---------------- degree histogram ----------------
__global__ void deg_kernel(const int* __restrict__ dst, int* __restrict__ deg) {
  int e = blockIdx.x * blockDim.x + threadIdx.x;
  if (e >= NE) return;
  atomicAdd(&deg[dst[e]], 1);
}

// ---------------- scan phase 1 ----------------
__global__ void scan_sum_kernel(const int* __restrict__ deg, int* __restrict__ bsum) {
  __shared__ int red[256];
  int t = threadIdx.x;
  int base = blockIdx.x * SCAN_CHUNK;
  int s = 0;
  for (int i = t; i < SCAN_CHUNK; i += 256) s += deg[base + i];
  red[t] = s;
  __syncthreads();
  for (int off = 128; off > 0; off >>= 1) {
    if (t < off) red[t] += red[t + off];
    __syncthreads();
  }
  if (t == 0) bsum[blockIdx.x] = red[0];
}

// ---------------- scan phase 2 ----------------
__global__ void scan_bsum_kernel(int* __restrict__ bsum, int* __restrict__ row_start) {
  __shared__ int sm[128];
  int t = threadIdx.x;
  int v = (t < SCAN_BLOCKS) ? bsum[t] : 0;
  sm[t] = v;
  __syncthreads();
  for (int off = 1; off < 128; off <<= 1) {
    int u = 0;
    if (t >= off) u = sm[t - off];
    __syncthreads();
    if (t >= off) sm[t] += u;
    __syncthreads();
  }
  if (t < SCAN_BLOCKS) bsum[t] = sm[t] - v;
  if (t == SCAN_BLOCKS - 1) row_start[NN] = sm[t];
}

// ---------------- scan phase 3 ----------------
__global__ void scan_final_kernel(const int* __restrict__ deg,
                                  const int* __restrict__ bsum,
                                  int* __restrict__ row_start,
                                  int* __restrict__ cursor) {
  __shared__ int sm[256];
  int t = threadIdx.x;
  int base = blockIdx.x * SCAN_CHUNK + t * 4;
  int4 d = {0, 0, 0, 0};
  if (t < 250) d = *reinterpret_cast<const int4*>(deg + base);
  int tot = d.x + d.y + d.z + d.w;
  sm[t] = tot;
  __syncthreads();
  for (int off = 1; off < 256; off <<= 1) {
    int u = 0;
    if (t >= off) u = sm[t - off];
    __syncthreads();
    if (t >= off) sm[t] += u;
    __syncthreads();
  }
  if (t < 250) {
    int run = bsum[blockIdx.x] + sm[t] - tot;
    int4 rs;
    rs.x = run;
    rs.y = run + d.x;
    rs.z = run + d.x + d.y;
    rs.w = run + d.x + d.y + d.z;
    *reinterpret_cast<int4*>(row_start + base) = rs;
    *reinterpret_cast<int4*>(cursor + base) = rs;
  }
}

// ---------------- fill CSR ----------------
__global__ void fill_csr_kernel(const int* __restrict__ src,
                                const int* __restrict__ dst,
                                int* __restrict__ cursor,
                                int* __restrict__ csr) {
  int e = blockIdx.x * blockDim.x + threadIdx.x;
  if (e >= NE) return;
  int pos = atomicAdd(&cursor[dst[e]], 1);
  csr[pos] = src[e];
}

// ---------------- hp = relu(x @ Wp + bp) fused with x->bf16; combined xh row ----------------
__global__ __launch_bounds__(512) void hp_gemm_kernel(const float* __restrict__ x,
                                                      const u16* __restrict__ wt,
                                                      const float* __restrict__ bp,
                                                      u16* __restrict__ xh) {
  __shared__ bf16x8 wl[1152];   // Wp^T
  int t = threadIdx.x;
  const bf16x8* wg = reinterpret_cast<const bf16x8*>(wt + 4 * 9216);
  for (int j = t; j < 1152; j += 512) wl[j] = wg[j];
  __syncthreads();
  int w = t >> 6, lane = t & 63;
  int i = lane & 15, g = lane >> 4;
  int row_base = blockIdx.x * 128 + w * 16;
  int grow_a = row_base + i;
  int lrow = grow_a < NN ? grow_a : NN - 1;
  const float4* xr = reinterpret_cast<const float4*>(x + (size_t)lrow * 96);
  bf16x8* xhv = reinterpret_cast<bf16x8*>(xh);
  bf16x8 ax[3];
#pragma unroll
  for (int kb = 0; kb < 3; ++kb) {
    float4 p = xr[(kb * 4 + g) * 2];
    float4 q = xr[(kb * 4 + g) * 2 + 1];
    bf16x8 v;
    v[0] = (short)f2b(p.x); v[1] = (short)f2b(p.y); v[2] = (short)f2b(p.z); v[3] = (short)f2b(p.w);
    v[4] = (short)f2b(q.x); v[5] = (short)f2b(q.y); v[6] = (short)f2b(q.z); v[7] = (short)f2b(q.w);
    ax[kb] = v;
    xhv[(size_t)grow_a * 24 + kb * 4 + g] = v;
  }
  for (int nt = 0; nt < 6; ++nt) {
    f32x4 acc = {0.f, 0.f, 0.f, 0.f};
    int bch = (nt * 16 + i) * 12;
#pragma unroll
    for (int kb = 0; kb < 3; ++kb)
      acc = MFMA16(ax[kb], wl[bch + kb * 4 + g], acc, 0, 0, 0);
    int col = nt * 16 + i;
    float bias = bp[col];
#pragma unroll
    for (int r = 0; r < 4; ++r) {
      int grow = row_base + g * 4 + r;
      xh[(size_t)grow * 192 + 96 + col] = f2b(fmaxf(acc[r] + bias, 0.0f));
    }
  }
}

// ---------------- fused gather: 32 nodes/block, 8 slots/node, 4-edge pipeline ----------------
__global__ __launch_bounds__(256) void gather_kernel(const u16* __restrict__ xh,
                                                     const int* __restrict__ row_start,
                                                     const int* __restrict__ csr,
                                                     u16* __restrict__ hmbf,
                                                     u16* __restrict__ hxbf) {
  int t = threadIdx.x;
  int node = blockIdx.x * 32 + (t & 31);
  int slot = t >> 5;            // 0..7; sum/max split at wave boundary
  bool isMax = slot >= 4;
  if (node >= NN) return;
  int beg = row_start[node], end = row_start[node + 1];
  int last = (end > beg) ? (end - 1) : 0;
  int cbase = slot * 3;
  const u16x8* XH = reinterpret_cast<const u16x8*>(xh);
  float s0[8], s1[8], s2[8];
  u16x8 m0, m1, m2;
#pragma unroll
  for (int j = 0; j < 8; ++j) {
    s0[j] = 0.f; s1[j] = 0.f; s2[j] = 0.f;
    m0[j] = 0; m1[j] = 0; m2[j] = 0;
  }
  int e = beg;
  int i0 = csr[(beg < end) ? beg : 0];
  int i1 = csr[(beg + 1 <= last) ? beg + 1 : last];
  int i2 = csr[(beg + 2 <= last) ? beg + 2 : last];
  int i3 = csr[(beg + 3 <= last) ? beg + 3 : last];
  for (; e + 4 <= end; e += 4) {
    int p = e + 4;
    int n0 = csr[(p     <= last) ? p     : last];
    int n1 = csr[(p + 1 <= last) ? p + 1 : last];
    int n2 = csr[(p + 2 <= last) ? p + 2 : last];
    int n3 = csr[(p + 3 <= last) ? p + 3 : last];
    size_t b0 = (size_t)i0 * 24 + cbase;
    size_t b1 = (size_t)i1 * 24 + cbase;
    size_t b2 = (size_t)i2 * 24 + cbase;
    size_t b3 = (size_t)i3 * 24 + cbase;
    u16x8 a0 = XH[b0], a1 = XH[b0 + 1], a2 = XH[b0 + 2];
    u16x8 c0 = XH[b1], c1 = XH[b1 + 1], c2 = XH[b1 + 2];
    u16x8 d0 = XH[b2], d1 = XH[b2 + 1], d2 = XH[b2 + 2];
    u16x8 f0 = XH[b3], f1 = XH[b3 + 1], f2 = XH[b3 + 2];
    if (isMax) {
#pragma unroll
      for (int j = 0; j < 8; ++j) {
        u16 p0 = a0[j] > c0[j] ? a0[j] : c0[j];
        u16 q0 = d0[j] > f0[j] ? d0[j] : f0[j];
        u16 r0 = p0 > q0 ? p0 : q0;
        m0[j] = m0[j] > r0 ? m0[j] : r0;
        u16 p1 = a1[j] > c1[j] ? a1[j] : c1[j];
        u16 q1 = d1[j] > f1[j] ? d1[j] : f1[j];
        u16 r1 = p1 > q1 ? p1 : q1;
        m1[j] = m1[j] > r1 ? m1[j] : r1;
        u16 p2 = a2[j] > c2[j] ? a2[j] : c2[j];
        u16 q2 = d2[j] > f2[j] ? d2[j] : f2[j];
        u16 r2 = p2 > q2 ? p2 : q2;
        m2[j] = m2[j] > r2 ? m2[j] : r2;
      }
    } else {
#pragma unroll
      for (int j = 0; j < 8; ++j) {
        s0[j] += (b2f((short)a0[j]) + b2f((short)c0[j])) + (b2f((short)d0[j]) + b2f((short)f0[j]));
        s1[j] += (b2f((short)a1[j]) + b2f((short)c1[j])) + (b2f((short)d1[j]) + b2f((short)f1[j]));
        s2[j] += (b2f((short)a2[j]) + b2f((short)c2[j])) + (b2f((short)d2[j]) + b2f((short)f2[j]));
      }
    }
    i0 = n0; i1 = n1; i2 = n2; i3 = n3;
  }
  // tail: up to 3 edges, indices already prefetched in i0..i2
  int rem = end - e;
#pragma unroll
  for (int k = 0; k < 3; ++k) {
    if (k < rem) {
      int ik = (k == 0) ? i0 : (k == 1) ? i1 : i2;
      size_t b0 = (size_t)ik * 24 + cbase;
      u16x8 a0 = XH[b0], a1 = XH[b0 + 1], a2 = XH[b0 + 2];
      if (isMax) {
#pragma unroll
        for (int j = 0; j < 8; ++j) {
          m0[j] = m0[j] > a0[j] ? m0[j] : a0[j];
          m1[j] = m1[j] > a1[j] ? m1[j] : a1[j];
          m2[j] = m2[j] > a2[j] ? m2[j] : a2[j];
        }
      } else {
#pragma unroll
        for (int j = 0; j < 8; ++j) {
          s0[j] += b2f((short)a0[j]);
          s1[j] += b2f((short)a1[j]);
          s2[j] += b2f((short)a2[j]);
        }
      }
    }
  }
  if (isMax) {
    u16x8* dv = reinterpret_cast<u16x8*>(hxbf);
    size_t ob = (size_t)node * 12 + (slot - 4) * 3;
    dv[ob] = m0; dv[ob + 1] = m1; dv[ob + 2] = m2;
  } else {
    float scl = (end > beg) ? 1.0f / (float)(end - beg) : 0.0f;
    u16x8 w0, w1, w2;
#pragma unroll
    for (int j = 0; j < 8; ++j) {
      w0[j] = f2b(s0[j] * scl);
      w1[j] = f2b(s1[j] * scl);
      w2[j] = f2b(s2[j] * scl);
    }
    u16x8* dv = reinterpret_cast<u16x8*>(hmbf);
    size_t ob = (size_t)node * 12 + slot * 3;
    dv[ob] = w0; dv[ob + 1] = w1; dv[ob + 2] = w2;
  }
}

// ---------------- pass 1: dual GEMM -> BN stats, split into two LDS phases ----------------
__global__ __launch_bounds__(512, 6) void stats_gemm_kernel(const u16* __restrict__ xh,
                                                            const u16* __restrict__ hmbf,
                                                            const u16* __restrict__ hxbf,
                                                            const u16* __restrict__ wt,
                                                            float* __restrict__ stats) {
  __shared__ bf16x8 wl[2304];   // two matrices at a time
  __shared__ float smst[384];
  int t = threadIdx.x;
  const bf16x8* wg = reinterpret_cast<const bf16x8*>(wt);
  for (int j = t; j < 2304; j += 512) wl[j] = wg[j];          // Ws1, Wn1
  for (int j = t; j < 384; j += 512) smst[j] = 0.f;
  __syncthreads();
  int w = t >> 6, lane = t & 63;
  int i = lane & 15, g = lane >> 4;
  int row_base = blockIdx.x * 128 + w * 16;
  size_t arowx = (size_t)(row_base + i) * 24;
  size_t arowh = (size_t)(row_base + i) * 12;
  const bf16x8* X = reinterpret_cast<const bf16x8*>(xh);
  const bf16x8* M = reinterpret_cast<const bf16x8*>(hmbf);
  const bf16x8* H = reinterpret_cast<const bf16x8*>(hxbf);
  bf16x8 ax0 = X[arowx + g], ax1 = X[arowx + 4 + g], ax2 = X[arowx + 8 + g];
  {
    bf16x8 am0 = M[arowh + g], am1 = M[arowh + 4 + g], am2 = M[arowh + 8 + g];
#pragma unroll
    for (int nt = 0; nt < 6; ++nt) {
      f32x4 a1 = {0.f, 0.f, 0.f, 0.f};
      int bch = (nt * 16 + i) * 12 + g;
      a1 = MFMA16(ax0, wl[bch], a1, 0, 0, 0);
      a1 = MFMA16(ax1, wl[bch + 4], a1, 0, 0, 0);
      a1 = MFMA16(ax2, wl[bch + 8], a1, 0, 0, 0);
      a1 = MFMA16(am0, wl[1152 + bch], a1, 0, 0, 0);
      a1 = MFMA16(am1, wl[1152 + bch + 4], a1, 0, 0, 0);
      a1 = MFMA16(am2, wl[1152 + bch + 8], a1, 0, 0, 0);
      int col = nt * 16 + i;
      float s1 = 0, q1 = 0;
#pragma unroll
      for (int r = 0; r < 4; ++r) {
        int grow = row_base + g * 4 + r;
        if (grow < NN) { float v = a1[r]; s1 += v; q1 += v * v; }
      }
      s1 += __shfl_xor(s1, 16); q1 += __shfl_xor(q1, 16);
      s1 += __shfl_xor(s1, 32); q1 += __shfl_xor(q1, 32);
      if (g == 0) {
        atomicAdd(&smst[col], s1);
        atomicAdd(&smst[96 + col], q1);
      }
    }
  }
  __syncthreads();
  for (int j = t; j < 2304; j += 512) wl[j] = wg[2304 + j];   // Ws2, Wn2
  __syncthreads();
  {
    bf16x8 ah0 = H[arowh + g], ah1 = H[arowh + 4 + g], ah2 = H[arowh + 8 + g];
#pragma unroll
    for (int nt = 0; nt < 6; ++nt) {
      f32x4 a2 = {0.f, 0.f, 0.f, 0.f};
      int bch = (nt * 16 + i) * 12 + g;
      a2 = MFMA16(ax0, wl[bch], a2, 0, 0, 0);
      a2 = MFMA16(ax1, wl[bch + 4], a2, 0, 0, 0);
      a2 = MFMA16(ax2, wl[bch + 8], a2, 0, 0, 0);
      a2 = MFMA16(ah0, wl[1152 + bch], a2, 0, 0, 0);
      a2 = MFMA16(ah1, wl[1152 + bch + 4], a2, 0, 0, 0);
      a2 = MFMA16(ah2, wl[1152 + bch + 8], a2, 0, 0, 0);
      int col = nt * 16 + i;
      float s2 = 0, q2 = 0;
#pragma unroll
      for (int r = 0; r < 4; ++r) {
        int grow = row_base + g * 4 + r;
        if (grow < NN) { float v = a2[r]; s2 += v; q2 += v * v; }
      }
      s2 += __shfl_xor(s2, 16); q2 += __shfl_xor(q2, 16);
      s2 += __shfl_xor(s2, 32); q2 += __shfl_xor(q2, 32);
      if (g == 0) {
        atomicAdd(&smst[192 + col], s2);
        atomicAdd(&smst[288 + col], q2);
      }
    }
  }
  __syncthreads();
  for (int j = t; j < 384; j += 512) atomicAdd(&stats[j], smst[j]);
}

// ---------------- pass 2: dual GEMM recompute + inline BN-fold -> fused output ----------------
__global__ __launch_bounds__(512, 4) void out_gemm_kernel(const u16* __restrict__ xh,
                                                          const u16* __restrict__ hmbf,
                                                          const u16* __restrict__ hxbf,
                                                          const u16* __restrict__ wt,
                                                          const float* __restrict__ stats,
                                                          const float* __restrict__ g1,
                                                          const float* __restrict__ beta1,
                                                          const float* __restrict__ g2,
                                                          const float* __restrict__ beta2,
                                                          float* __restrict__ out) {
  __shared__ bf16x8 wl[2304];
  __shared__ float pl[384];
  int t = threadIdx.x;
  const bf16x8* wg = reinterpret_cast<const bf16x8*>(wt);
  for (int j = t; j < 2304; j += 512) wl[j] = wg[j];          // Ws1, Wn1
  if (t < 96) {                                               // inline finalize
    const float inv_n = 1.0f / NN;
    float mu1 = stats[t] * inv_n;
    float var1 = fmaxf(stats[96 + t] * inv_n - mu1 * mu1, 0.0f);
    float a1 = g1[t] * rsqrtf(var1 + 1e-5f);
    pl[t] = a1;
    pl[96 + t] = beta1[t] - a1 * mu1;
    float mu2 = stats[192 + t] * inv_n;
    float var2 = fmaxf(stats[288 + t] * inv_n - mu2 * mu2, 0.0f);
    float a2 = g2[t] * rsqrtf(var2 + 1e-5f);
    pl[192 + t] = a2;
    pl[288 + t] = beta2[t] - a2 * mu2;
  }
  __syncthreads();
  int w = t >> 6, lane = t & 63;
  int i = lane & 15, g = lane >> 4;
  int row_base = blockIdx.x * 128 + w * 16;
  size_t arowx = (size_t)(row_base + i) * 24;
  size_t arowh = (size_t)(row_base + i) * 12;
  const bf16x8* X = reinterpret_cast<const bf16x8*>(xh);
  const bf16x8* M = reinterpret_cast<const bf16x8*>(hmbf);
  const bf16x8* H = reinterpret_cast<const bf16x8*>(hxbf);
  bf16x8 ax0 = X[arowx + g], ax1 = X[arowx + 4 + g], ax2 = X[arowx + 8 + g];
  f32x4 o1[6];
  {
    bf16x8 am0 = M[arowh + g], am1 = M[arowh + 4 + g], am2 = M[arowh + 8 + g];
#pragma unroll
    for (int nt = 0; nt < 6; ++nt) {
      f32x4 a1 = {0.f, 0.f, 0.f, 0.f};
      int bch = (nt * 16 + i) * 12 + g;
      a1 = MFMA16(ax0, wl[bch], a1, 0, 0, 0);
      a1 = MFMA16(ax1, wl[bch + 4], a1, 0, 0, 0);
      a1 = MFMA16(ax2, wl[bch + 8], a1, 0, 0, 0);
      a1 = MFMA16(am0, wl[1152 + bch], a1, 0, 0, 0);
      a1 = MFMA16(am1, wl[1152 + bch + 4], a1, 0, 0, 0);
      a1 = MFMA16(am2, wl[1152 + bch + 8], a1, 0, 0, 0);
      o1[nt] = a1;
    }
  }
  __syncthreads();
  for (int j = t; j < 2304; j += 512) wl[j] = wg[2304 + j];   // Ws2, Wn2
  __syncthreads();
  {
    bf16x8 ah0 = H[arowh + g], ah1 = H[arowh + 4 + g], ah2 = H[arowh + 8 + g];
#pragma unroll
    for (int nt = 0; nt < 6; ++nt) {
      f32x4 a2 = {0.f, 0.f, 0.f, 0.f};
      int bch = (nt * 16 + i) * 12 + g;
      a2 = MFMA16(ax0, wl[bch], a2, 0, 0, 0);
      a2 = MFMA16(ax1, wl[bch + 4], a2, 0, 0, 0);
      a2 = MFMA16(ax2, wl[bch + 8], a2, 0, 0, 0);
      a2 = MFMA16(ah0, wl[1152 + bch], a2, 0, 0, 0);
      a2 = MFMA16(ah1, wl[1152 + bch + 4], a2, 0, 0, 0);
      a2 = MFMA16(ah2, wl[1152 + bch + 8], a2, 0, 0, 0);
      int col = nt * 16 + i;
      float p1 = pl[col], c1 = pl[96 + col];
      float p2 = pl[192 + col], c2 = pl[288 + col];
#pragma unroll
      for (int r = 0; r < 4; ++r) {
        int grow = row_base + g * 4 + r;
        if (grow < NN) {
          float v = p1 * o1[nt][r] + c1 + p2 * a2[r] + c2;
          v = v > 0.f ? v : 0.01f * v;
          out[(size_t)grow * 96 + col] = v;
        }
      }
    }
  }
}

extern "C" void kernel_launch(void* const* d_in, const int* in_sizes, int n_in,
                              void* d_out, int out_size, void* d_ws, size_t ws_size,
                              hipStream_t stream) {
  const float* x       = (const float*)d_in[0];
  const int*   ei      = (const int*)d_in[1];
  const float* W_self1 = (const float*)d_in[2];
  const float* W_neigh1= (const float*)d_in[3];
  const float* W_pool  = (const float*)d_in[4];
  const float* b_pool  = (const float*)d_in[5];
  const float* W_self2 = (const float*)d_in[6];
  const float* W_neigh2= (const float*)d_in[7];
  const float* g1      = (const float*)d_in[8];
  const float* beta1   = (const float*)d_in[9];
  const float* g2      = (const float*)d_in[10];
  const float* beta2   = (const float*)d_in[11];
  float* out = (float*)d_out;

  float* ws = (float*)d_ws;
  int*   deg       = (int*)(ws + OFF_DEG);
  int*   row_start = (int*)(ws + OFF_ROWSTART);
  int*   cursor    = (int*)(ws + OFF_CURSOR);
  int*   bsum      = (int*)(ws + OFF_BSUM);
  float* stats     = ws + OFF_STATS;
  u16*   wt        = (u16*)(ws + OFF_WT);
  int*   csr       = (int*)(ws + OFF_CSR);
  u16*   xh        = (u16*)(ws + OFF_XH);
  u16*   hmbf      = (u16*)(ws + OFF_HMBF);
  u16*   hxbf      = (u16*)(ws + OFF_HXBF);

  const int* src = ei;
  const int* dst = ei + NE;

  hipMemsetAsync(deg, 0, NN * sizeof(int), stream);
  hipMemsetAsync(stats, 0, 384 * sizeof(float), stream);

  wprep_kernel<<<(5 * 9216 + 255) / 256, 256, 0, stream>>>(W_self1, W_neigh1, W_self2,
                                                           W_neigh2, W_pool, wt);

  deg_kernel<<<(NE + 255) / 256, 256, 0, stream>>>(dst, deg);
  scan_sum_kernel<<<SCAN_BLOCKS, 256, 0, stream>>>(deg, bsum);
  scan_bsum_kernel<<<1, 128, 0, stream>>>(bsum, row_start);
  scan_final_kernel<<<SCAN_BLOCKS, 256, 0, stream>>>(deg, bsum, row_start, cursor);
  fill_csr_kernel<<<(NE + 255) / 256, 256, 0, stream>>>(src, dst, cursor, csr);

  hp_gemm_kernel<<<GBLK, 512, 0, stream>>>(x, wt, b_pool, xh);

  gather_kernel<<<(NN + 31) / 32, 256, 0, stream>>>(xh, row_start, csr, hmbf, hxbf);

  stats_gemm_kernel<<<GBLK, 512, 0, stream>>>(xh, hmbf, hxbf, wt, stats);
  out_gemm_kernel<<<GBLK, 512, 0, stream>>>(xh, hmbf, hxbf, wt, stats,
                                            g1, beta1, g2, beta2, out);
}

// Round 14
// 259.249 us; speedup vs baseline: 2.4433x; 1.0128x over previous
//
#include <hip/hip_runtime.h>

#define NN 100000
#define NE 800000
#define DD 96
#define NROWPAD 100096            // 782 * 128
#define GBLK 782                  // GEMM blocks (128 rows each)
#define SCAN_BLOCKS 100
#define SCAN_CHUNK 1000

typedef __attribute__((ext_vector_type(8))) short bf16x8;
typedef __attribute__((ext_vector_type(8))) unsigned short u16x8;
typedef __attribute__((ext_vector_type(4))) float f32x4;
typedef unsigned short u16;
typedef unsigned int u32;

#define MFMA16 __builtin_amdgcn_mfma_f32_16x16x32_bf16

// workspace layout (4-byte element offsets)
#define OFF_DEG      0u          // NN ints
#define OFF_ROWSTART 100000u     // NN+1 ints
#define OFF_CURSOR   200004u     // NN ints
#define OFF_BSUM     300004u     // 128 ints
#define OFF_STATS    302180u     // 384 floats
#define OFF_PARAMS   302564u     // 384 floats
#define OFF_WT       302948u     // 5*9216 bf16 = 23040 floats
#define OFF_CSR      325988u     // NE ints
#define OFF_XH       1125988u    // NROWPAD*96 floats (combined x|hp bf16 rows, 384B)
#define OFF_HMBF     10735204u   // NROWPAD*48 floats -> becomes o1 (bf16)
#define OFF_HXBF     15539812u   // NROWPAD*48 floats -> becomes o2 (bf16)

__device__ __forceinline__ u16 f2b(float f) {
  u32 u = __float_as_uint(f);
  u += 0x7FFFu + ((u >> 16) & 1u);
  return (u16)(u >> 16);
}
__device__ __forceinline__ float b2f(short h) {
  return __uint_as_float(((u32)(u16)h) << 16);
}

// ---------------- weight prep ----------------
__global__ void wprep_kernel(const float* __restrict__ Ws1, const float* __restrict__ Wn1,
                             const float* __restrict__ Ws2, const float* __restrict__ Wn2,
                             const float* __restrict__ Wp, u16* __restrict__ wt) {
  int idx = blockIdx.x * 256 + threadIdx.x;
  if (idx >= 5 * 9216) return;
  int m = idx / 9216, r = idx % 9216;
  int k = r / 96, c = r % 96;
  const float* W = (m == 0) ? Ws1 : (m == 1) ? Wn1 : (m == 2) ? Ws2 : (m == 3) ? Wn2 : Wp;
  wt[m * 9216 + c * 96 + k] = f2b(W[k * 96 + c]);
}

// ---------------- degree histogram ----------------
__global__ void deg_kernel(const int* __restrict__ dst, int* __restrict__ deg) {
  int e = blockIdx.x * blockDim.x + threadIdx.x;
  if (e >= NE) return;
  atomicAdd(&deg[dst[e]], 1);
}

// ---------------- scan phase 1 ----------------
__global__ void scan_sum_kernel(const int* __restrict__ deg, int* __restrict__ bsum) {
  __shared__ int red[256];
  int t = threadIdx.x;
  int base = blockIdx.x * SCAN_CHUNK;
  int s = 0;
  for (int i = t; i < SCAN_CHUNK; i += 256) s += deg[base + i];
  red[t] = s;
  __syncthreads();
  for (int off = 128; off > 0; off >>= 1) {
    if (t < off) red[t] += red[t + off];
    __syncthreads();
  }
  if (t == 0) bsum[blockIdx.x] = red[0];
}

// ---------------- scan phase 2 ----------------
__global__ void scan_bsum_kernel(int* __restrict__ bsum, int* __restrict__ row_start) {
  __shared__ int sm[128];
  int t = threadIdx.x;
  int v = (t < SCAN_BLOCKS) ? bsum[t] : 0;
  sm[t] = v;
  __syncthreads();
  for (int off = 1; off < 128; off <<= 1) {
    int u = 0;
    if (t >= off) u = sm[t - off];
    __syncthreads();
    if (t >= off) sm[t] += u;
    __syncthreads();
  }
  if (t < SCAN_BLOCKS) bsum[t] = sm[t] - v;
  if (t == SCAN_BLOCKS - 1) row_start[NN] = sm[t];
}

// ---------------- scan phase 3 ----------------
__global__ void scan_final_kernel(const int* __restrict__ deg,
                                  const int* __restrict__ bsum,
                                  int* __restrict__ row_start,
                                  int* __restrict__ cursor) {
  __shared__ int sm[256];
  int t = threadIdx.x;
  int base = blockIdx.x * SCAN_CHUNK + t * 4;
  int4 d = {0, 0, 0, 0};
  if (t < 250) d = *reinterpret_cast<const int4*>(deg + base);
  int tot = d.x + d.y + d.z + d.w;
  sm[t] = tot;
  __syncthreads();
  for (int off = 1; off < 256; off <<= 1) {
    int u = 0;
    if (t >= off) u = sm[t - off];
    __syncthreads();
    if (t >= off) sm[t] += u;
    __syncthreads();
  }
  if (t < 250) {
    int run = bsum[blockIdx.x] + sm[t] - tot;
    int4 rs;
    rs.x = run;
    rs.y = run + d.x;
    rs.z = run + d.x + d.y;
    rs.w = run + d.x + d.y + d.z;
    *reinterpret_cast<int4*>(row_start + base) = rs;
    *reinterpret_cast<int4*>(cursor + base) = rs;
  }
}

// ---------------- fill CSR ----------------
__global__ void fill_csr_kernel(const int* __restrict__ src,
                                const int* __restrict__ dst,
                                int* __restrict__ cursor,
                                int* __restrict__ csr) {
  int e = blockIdx.x * blockDim.x + threadIdx.x;
  if (e >= NE) return;
  int pos = atomicAdd(&cursor[dst[e]], 1);
  csr[pos] = src[e];
}

// ---------------- hp = relu(x @ Wp + bp) fused with x->bf16; combined xh row ----------------
__global__ __launch_bounds__(512) void hp_gemm_kernel(const float* __restrict__ x,
                                                      const u16* __restrict__ wt,
                                                      const float* __restrict__ bp,
                                                      u16* __restrict__ xh) {
  __shared__ bf16x8 wl[1152];   // Wp^T
  int t = threadIdx.x;
  const bf16x8* wg = reinterpret_cast<const bf16x8*>(wt + 4 * 9216);
  for (int j = t; j < 1152; j += 512) wl[j] = wg[j];
  __syncthreads();
  int w = t >> 6, lane = t & 63;
  int i = lane & 15, g = lane >> 4;
  int row_base = blockIdx.x * 128 + w * 16;
  int grow_a = row_base + i;
  int lrow = grow_a < NN ? grow_a : NN - 1;
  const float4* xr = reinterpret_cast<const float4*>(x + (size_t)lrow * 96);
  bf16x8* xhv = reinterpret_cast<bf16x8*>(xh);
  bf16x8 ax[3];
#pragma unroll
  for (int kb = 0; kb < 3; ++kb) {
    float4 p = xr[(kb * 4 + g) * 2];
    float4 q = xr[(kb * 4 + g) * 2 + 1];
    bf16x8 v;
    v[0] = (short)f2b(p.x); v[1] = (short)f2b(p.y); v[2] = (short)f2b(p.z); v[3] = (short)f2b(p.w);
    v[4] = (short)f2b(q.x); v[5] = (short)f2b(q.y); v[6] = (short)f2b(q.z); v[7] = (short)f2b(q.w);
    ax[kb] = v;
    xhv[(size_t)grow_a * 24 + kb * 4 + g] = v;
  }
  for (int nt = 0; nt < 6; ++nt) {
    f32x4 acc = {0.f, 0.f, 0.f, 0.f};
    int bch = (nt * 16 + i) * 12;
#pragma unroll
    for (int kb = 0; kb < 3; ++kb)
      acc = MFMA16(ax[kb], wl[bch + kb * 4 + g], acc, 0, 0, 0);
    int col = nt * 16 + i;
    float bias = bp[col];
#pragma unroll
    for (int r = 0; r < 4; ++r) {
      int grow = row_base + g * 4 + r;
      xh[(size_t)grow * 192 + 96 + col] = f2b(fmaxf(acc[r] + bias, 0.0f));
    }
  }
}

// ---------------- fused gather: 32 nodes/block, 8 slots/node, 4-edge pipeline ----------------
__global__ __launch_bounds__(256) void gather_kernel(const u16* __restrict__ xh,
                                                     const int* __restrict__ row_start,
                                                     const int* __restrict__ csr,
                                                     u16* __restrict__ hmbf,
                                                     u16* __restrict__ hxbf) {
  int t = threadIdx.x;
  int node = blockIdx.x * 32 + (t & 31);
  int slot = t >> 5;            // 0..7; sum/max split at wave boundary
  bool isMax = slot >= 4;
  if (node >= NN) return;
  int beg = row_start[node], end = row_start[node + 1];
  int last = (end > beg) ? (end - 1) : 0;
  int cbase = slot * 3;
  const u16x8* XH = reinterpret_cast<const u16x8*>(xh);
  float s0[8], s1[8], s2[8];
  u16x8 m0, m1, m2;
#pragma unroll
  for (int j = 0; j < 8; ++j) {
    s0[j] = 0.f; s1[j] = 0.f; s2[j] = 0.f;
    m0[j] = 0; m1[j] = 0; m2[j] = 0;
  }
  int e = beg;
  int i0 = csr[(beg < end) ? beg : 0];
  int i1 = csr[(beg + 1 <= last) ? beg + 1 : last];
  int i2 = csr[(beg + 2 <= last) ? beg + 2 : last];
  int i3 = csr[(beg + 3 <= last) ? beg + 3 : last];
  for (; e + 4 <= end; e += 4) {
    int p = e + 4;
    int n0 = csr[(p     <= last) ? p     : last];
    int n1 = csr[(p + 1 <= last) ? p + 1 : last];
    int n2 = csr[(p + 2 <= last) ? p + 2 : last];
    int n3 = csr[(p + 3 <= last) ? p + 3 : last];
    size_t b0 = (size_t)i0 * 24 + cbase;
    size_t b1 = (size_t)i1 * 24 + cbase;
    size_t b2 = (size_t)i2 * 24 + cbase;
    size_t b3 = (size_t)i3 * 24 + cbase;
    u16x8 a0 = XH[b0], a1 = XH[b0 + 1], a2 = XH[b0 + 2];
    u16x8 c0 = XH[b1], c1 = XH[b1 + 1], c2 = XH[b1 + 2];
    u16x8 d0 = XH[b2], d1 = XH[b2 + 1], d2 = XH[b2 + 2];
    u16x8 f0 = XH[b3], f1 = XH[b3 + 1], f2 = XH[b3 + 2];
    if (isMax) {
#pragma unroll
      for (int j = 0; j < 8; ++j) {
        u16 p0 = a0[j] > c0[j] ? a0[j] : c0[j];
        u16 q0 = d0[j] > f0[j] ? d0[j] : f0[j];
        u16 r0 = p0 > q0 ? p0 : q0;
        m0[j] = m0[j] > r0 ? m0[j] : r0;
        u16 p1 = a1[j] > c1[j] ? a1[j] : c1[j];
        u16 q1 = d1[j] > f1[j] ? d1[j] : f1[j];
        u16 r1 = p1 > q1 ? p1 : q1;
        m1[j] = m1[j] > r1 ? m1[j] : r1;
        u16 p2 = a2[j] > c2[j] ? a2[j] : c2[j];
        u16 q2 = d2[j] > f2[j] ? d2[j] : f2[j];
        u16 r2 = p2 > q2 ? p2 : q2;
        m2[j] = m2[j] > r2 ? m2[j] : r2;
      }
    } else {
#pragma unroll
      for (int j = 0; j < 8; ++j) {
        s0[j] += (b2f((short)a0[j]) + b2f((short)c0[j])) + (b2f((short)d0[j]) + b2f((short)f0[j]));
        s1[j] += (b2f((short)a1[j]) + b2f((short)c1[j])) + (b2f((short)d1[j]) + b2f((short)f1[j]));
        s2[j] += (b2f((short)a2[j]) + b2f((short)c2[j])) + (b2f((short)d2[j]) + b2f((short)f2[j]));
      }
    }
    i0 = n0; i1 = n1; i2 = n2; i3 = n3;
  }
  int rem = end - e;
#pragma unroll
  for (int k = 0; k < 3; ++k) {
    if (k < rem) {
      int ik = (k == 0) ? i0 : (k == 1) ? i1 : i2;
      size_t b0 = (size_t)ik * 24 + cbase;
      u16x8 a0 = XH[b0], a1 = XH[b0 + 1], a2 = XH[b0 + 2];
      if (isMax) {
#pragma unroll
        for (int j = 0; j < 8; ++j) {
          m0[j] = m0[j] > a0[j] ? m0[j] : a0[j];
          m1[j] = m1[j] > a1[j] ? m1[j] : a1[j];
          m2[j] = m2[j] > a2[j] ? m2[j] : a2[j];
        }
      } else {
#pragma unroll
        for (int j = 0; j < 8; ++j) {
          s0[j] += b2f((short)a0[j]);
          s1[j] += b2f((short)a1[j]);
          s2[j] += b2f((short)a2[j]);
        }
      }
    }
  }
  if (isMax) {
    u16x8* dv = reinterpret_cast<u16x8*>(hxbf);
    size_t ob = (size_t)node * 12 + (slot - 4) * 3;
    dv[ob] = m0; dv[ob + 1] = m1; dv[ob + 2] = m2;
  } else {
    float scl = (end > beg) ? 1.0f / (float)(end - beg) : 0.0f;
    u16x8 w0, w1, w2;
#pragma unroll
    for (int j = 0; j < 8; ++j) {
      w0[j] = f2b(s0[j] * scl);
      w1[j] = f2b(s1[j] * scl);
      w2[j] = f2b(s2[j] * scl);
    }
    u16x8* dv = reinterpret_cast<u16x8*>(hmbf);
    size_t ob = (size_t)node * 12 + slot * 3;
    dv[ob] = w0; dv[ob + 1] = w1; dv[ob + 2] = w2;
  }
}

// ---------------- single fused o-GEMM: o1,o2 bf16 (LDS transpose, coalesced) + BN stats ----
// phase 1: o1 = x@Ws1 + hm@Wn1  -> stats + bf16 store over hmbf (block-local rows)
// phase 2: o2 = x@Ws2 + hx@Wn2  -> stats + bf16 store over hxbf
__global__ __launch_bounds__(512, 4) void ogemm_kernel(const u16* __restrict__ xh,
                                                       u16* __restrict__ hmbf,
                                                       u16* __restrict__ hxbf,
                                                       const u16* __restrict__ wt,
                                                       float* __restrict__ stats) {
  __shared__ bf16x8 wl[2304];                 // two matrices at a time
  __shared__ float smst[384];
  __shared__ __align__(16) u16 ot[128][104];  // o tile, padded rows (208B, 16B-aligned)
  int t = threadIdx.x;
  const bf16x8* wg = reinterpret_cast<const bf16x8*>(wt);
  for (int j = t; j < 2304; j += 512) wl[j] = wg[j];          // Ws1, Wn1
  for (int j = t; j < 384; j += 512) smst[j] = 0.f;
  __syncthreads();
  int w = t >> 6, lane = t & 63;
  int i = lane & 15, g = lane >> 4;
  int row_base = blockIdx.x * 128 + w * 16;
  int row0 = blockIdx.x * 128;
  size_t arowx = (size_t)(row_base + i) * 24;
  size_t arowh = (size_t)(row_base + i) * 12;
  const bf16x8* X = reinterpret_cast<const bf16x8*>(xh);
  const bf16x8* M = reinterpret_cast<const bf16x8*>(hmbf);
  const bf16x8* H = reinterpret_cast<const bf16x8*>(hxbf);
  bf16x8 ax0 = X[arowx + g], ax1 = X[arowx + 4 + g], ax2 = X[arowx + 8 + g];
  // ---- phase 1: o1 ----
  {
    bf16x8 am0 = M[arowh + g], am1 = M[arowh + 4 + g], am2 = M[arowh + 8 + g];
#pragma unroll
    for (int nt = 0; nt < 6; ++nt) {
      f32x4 a1 = {0.f, 0.f, 0.f, 0.f};
      int bch = (nt * 16 + i) * 12 + g;
      a1 = MFMA16(ax0, wl[bch], a1, 0, 0, 0);
      a1 = MFMA16(ax1, wl[bch + 4], a1, 0, 0, 0);
      a1 = MFMA16(ax2, wl[bch + 8], a1, 0, 0, 0);
      a1 = MFMA16(am0, wl[1152 + bch], a1, 0, 0, 0);
      a1 = MFMA16(am1, wl[1152 + bch + 4], a1, 0, 0, 0);
      a1 = MFMA16(am2, wl[1152 + bch + 8], a1, 0, 0, 0);
      int col = nt * 16 + i;
      float s1 = 0, q1 = 0;
#pragma unroll
      for (int r = 0; r < 4; ++r) {
        int lrow = w * 16 + g * 4 + r;
        ot[lrow][col] = f2b(a1[r]);
        if (row0 + lrow < NN) { float v = a1[r]; s1 += v; q1 += v * v; }
      }
      s1 += __shfl_xor(s1, 16); q1 += __shfl_xor(q1, 16);
      s1 += __shfl_xor(s1, 32); q1 += __shfl_xor(q1, 32);
      if (g == 0) {
        atomicAdd(&smst[col], s1);
        atomicAdd(&smst[96 + col], q1);
      }
    }
  }
  __syncthreads();
  // write o1 tile coalesced + restage weights (Ws2, Wn2)
  {
    u16x8* dv = reinterpret_cast<u16x8*>(hmbf);
#pragma unroll
    for (int c = 0; c < 3; ++c) {
      int ci = t + c * 512;
      int r = ci / 12, cc = ci % 12;
      u16x8 v = *reinterpret_cast<const u16x8*>(&ot[r][cc * 8]);
      dv[(size_t)(row0 + r) * 12 + cc] = v;
    }
    for (int j = t; j < 2304; j += 512) wl[j] = wg[2304 + j];
  }
  __syncthreads();
  // ---- phase 2: o2 ----
  {
    bf16x8 ah0 = H[arowh + g], ah1 = H[arowh + 4 + g], ah2 = H[arowh + 8 + g];
#pragma unroll
    for (int nt = 0; nt < 6; ++nt) {
      f32x4 a2 = {0.f, 0.f, 0.f, 0.f};
      int bch = (nt * 16 + i) * 12 + g;
      a2 = MFMA16(ax0, wl[bch], a2, 0, 0, 0);
      a2 = MFMA16(ax1, wl[bch + 4], a2, 0, 0, 0);
      a2 = MFMA16(ax2, wl[bch + 8], a2, 0, 0, 0);
      a2 = MFMA16(ah0, wl[1152 + bch], a2, 0, 0, 0);
      a2 = MFMA16(ah1, wl[1152 + bch + 4], a2, 0, 0, 0);
      a2 = MFMA16(ah2, wl[1152 + bch + 8], a2, 0, 0, 0);
      int col = nt * 16 + i;
      float s2 = 0, q2 = 0;
#pragma unroll
      for (int r = 0; r < 4; ++r) {
        int lrow = w * 16 + g * 4 + r;
        ot[lrow][col] = f2b(a2[r]);
        if (row0 + lrow < NN) { float v = a2[r]; s2 += v; q2 += v * v; }
      }
      s2 += __shfl_xor(s2, 16); q2 += __shfl_xor(q2, 16);
      s2 += __shfl_xor(s2, 32); q2 += __shfl_xor(q2, 32);
      if (g == 0) {
        atomicAdd(&smst[192 + col], s2);
        atomicAdd(&smst[288 + col], q2);
      }
    }
  }
  __syncthreads();
  {
    u16x8* dv = reinterpret_cast<u16x8*>(hxbf);
#pragma unroll
    for (int c = 0; c < 3; ++c) {
      int ci = t + c * 512;
      int r = ci / 12, cc = ci % 12;
      u16x8 v = *reinterpret_cast<const u16x8*>(&ot[r][cc * 8]);
      dv[(size_t)(row0 + r) * 12 + cc] = v;
    }
  }
  for (int j = t; j < 384; j += 512) atomicAdd(&stats[j], smst[j]);
}

// ---------------- fold BN into per-column affine ----------------
__global__ void finalize_kernel(const float* __restrict__ stats,
                                const float* __restrict__ g1, const float* __restrict__ beta1,
                                const float* __restrict__ g2, const float* __restrict__ beta2,
                                float* __restrict__ params) {
  int c = threadIdx.x;
  if (c >= 96) return;
  const float inv_n = 1.0f / NN;
  float mu1 = stats[c] * inv_n;
  float var1 = fmaxf(stats[96 + c] * inv_n - mu1 * mu1, 0.0f);
  float is1 = rsqrtf(var1 + 1e-5f);
  float a1 = g1[c] * is1;
  params[c] = a1;
  params[96 + c] = beta1[c] - a1 * mu1;
  float mu2 = stats[192 + c] * inv_n;
  float var2 = fmaxf(stats[288 + c] * inv_n - mu2 * mu2, 0.0f);
  float is2 = rsqrtf(var2 + 1e-5f);
  float a2 = g2[c] * is2;
  params[192 + c] = a2;
  params[288 + c] = beta2[c] - a2 * mu2;
}

// ---------------- out = leaky(bn1(o1)+bn2(o2)), streaming ----------------
__global__ __launch_bounds__(256) void final_kernel(const u16* __restrict__ o1,
                                                    const u16* __restrict__ o2,
                                                    const float* __restrict__ params,
                                                    float* __restrict__ out) {
  int idx = blockIdx.x * 256 + threadIdx.x;   // one bf16x8 chunk
  if (idx >= NN * 12) return;
  int c8 = idx % 12;
  bf16x8 v1 = reinterpret_cast<const bf16x8*>(o1)[idx];
  bf16x8 v2 = reinterpret_cast<const bf16x8*>(o2)[idx];
  const float4* P = reinterpret_cast<const float4*>(params);
  float4 A1l = P[c8 * 2],      A1h = P[c8 * 2 + 1];
  float4 B1l = P[24 + c8 * 2], B1h = P[24 + c8 * 2 + 1];
  float4 A2l = P[48 + c8 * 2], A2h = P[48 + c8 * 2 + 1];
  float4 B2l = P[72 + c8 * 2], B2h = P[72 + c8 * 2 + 1];
  float A1[8] = {A1l.x, A1l.y, A1l.z, A1l.w, A1h.x, A1h.y, A1h.z, A1h.w};
  float B1[8] = {B1l.x, B1l.y, B1l.z, B1l.w, B1h.x, B1h.y, B1h.z, B1h.w};
  float A2[8] = {A2l.x, A2l.y, A2l.z, A2l.w, A2h.x, A2h.y, A2h.z, A2h.w};
  float B2[8] = {B2l.x, B2l.y, B2l.z, B2l.w, B2h.x, B2h.y, B2h.z, B2h.w};
  float o[8];
#pragma unroll
  for (int j = 0; j < 8; ++j) {
    float v = A1[j] * b2f((short)v1[j]) + B1[j] + A2[j] * b2f((short)v2[j]) + B2[j];
    o[j] = v > 0.f ? v : 0.01f * v;
  }
  float4* ov = reinterpret_cast<float4*>(out);
  float4 lo = {o[0], o[1], o[2], o[3]}, hi = {o[4], o[5], o[6], o[7]};
  ov[idx * 2] = lo;
  ov[idx * 2 + 1] = hi;
}

extern "C" void kernel_launch(void* const* d_in, const int* in_sizes, int n_in,
                              void* d_out, int out_size, void* d_ws, size_t ws_size,
                              hipStream_t stream) {
  const float* x       = (const float*)d_in[0];
  const int*   ei      = (const int*)d_in[1];
  const float* W_self1 = (const float*)d_in[2];
  const float* W_neigh1= (const float*)d_in[3];
  const float* W_pool  = (const float*)d_in[4];
  const float* b_pool  = (const float*)d_in[5];
  const float* W_self2 = (const float*)d_in[6];
  const float* W_neigh2= (const float*)d_in[7];
  const float* g1      = (const float*)d_in[8];
  const float* beta1   = (const float*)d_in[9];
  const float* g2      = (const float*)d_in[10];
  const float* beta2   = (const float*)d_in[11];
  float* out = (float*)d_out;

  float* ws = (float*)d_ws;
  int*   deg       = (int*)(ws + OFF_DEG);
  int*   row_start = (int*)(ws + OFF_ROWSTART);
  int*   cursor    = (int*)(ws + OFF_CURSOR);
  int*   bsum      = (int*)(ws + OFF_BSUM);
  float* stats     = ws + OFF_STATS;
  float* params    = ws + OFF_PARAMS;
  u16*   wt        = (u16*)(ws + OFF_WT);
  int*   csr       = (int*)(ws + OFF_CSR);
  u16*   xh        = (u16*)(ws + OFF_XH);
  u16*   hmbf      = (u16*)(ws + OFF_HMBF);
  u16*   hxbf      = (u16*)(ws + OFF_HXBF);

  const int* src = ei;
  const int* dst = ei + NE;

  hipMemsetAsync(deg, 0, NN * sizeof(int), stream);
  hipMemsetAsync(stats, 0, 384 * sizeof(float), stream);

  wprep_kernel<<<(5 * 9216 + 255) / 256, 256, 0, stream>>>(W_self1, W_neigh1, W_self2,
                                                           W_neigh2, W_pool, wt);

  deg_kernel<<<(NE + 255) / 256, 256, 0, stream>>>(dst, deg);
  scan_sum_kernel<<<SCAN_BLOCKS, 256, 0, stream>>>(deg, bsum);
  scan_bsum_kernel<<<1, 128, 0, stream>>>(bsum, row_start);
  scan_final_kernel<<<SCAN_BLOCKS, 256, 0, stream>>>(deg, bsum, row_start, cursor);
  fill_csr_kernel<<<(NE + 255) / 256, 256, 0, stream>>>(src, dst, cursor, csr);

  hp_gemm_kernel<<<GBLK, 512, 0, stream>>>(x, wt, b_pool, xh);

  gather_kernel<<<(NN + 31) / 32, 256, 0, stream>>>(xh, row_start, csr, hmbf, hxbf);

  // fused: o1/o2 (bf16, in place over hm/hx) + BN stats
  ogemm_kernel<<<GBLK, 512, 0, stream>>>(xh, hmbf, hxbf, wt, stats);
  finalize_kernel<<<1, 128, 0, stream>>>(stats, g1, beta1, g2, beta2, params);
  final_kernel<<<(NN * 12 + 255) / 256, 256, 0, stream>>>(hmbf, hxbf, params, out);
}

// Round 15
// 255.856 us; speedup vs baseline: 2.4757x; 1.0133x over previous
//
#include <hip/hip_runtime.h>

#define NN 100000
#define NE 800000
#define DD 96
#define NROWPAD 100096            // 782 * 128
#define GBLK 782                  // GEMM blocks (128 rows each)
#define SCAN_BLOCKS 100
#define SCAN_CHUNK 1000

typedef __attribute__((ext_vector_type(8))) short bf16x8;
typedef __attribute__((ext_vector_type(8))) unsigned short u16x8;
typedef __attribute__((ext_vector_type(4))) float f32x4;
typedef unsigned short u16;
typedef unsigned int u32;

#define MFMA16 __builtin_amdgcn_mfma_f32_16x16x32_bf16

// workspace layout (4-byte element offsets)
#define OFF_DEG      0u          // NN ints
#define OFF_ROWSTART 100000u     // NN+1 ints
#define OFF_CURSOR   200004u     // NN ints
#define OFF_BSUM     300004u     // 128 ints
#define OFF_STATS    302180u     // 384 floats
#define OFF_WT       302948u     // 5*9216 bf16 = 23040 floats
#define OFF_CSR      325988u     // NE ints
#define OFF_XH       1125988u    // NROWPAD*96 floats (combined x|hp bf16 rows, 384B)
#define OFF_HMBF     10735204u   // NROWPAD*48 floats -> becomes o1 (bf16)
#define OFF_HXBF     15539812u   // NROWPAD*48 floats -> becomes o2 (bf16)

__device__ __forceinline__ u16 f2b(float f) {
  u32 u = __float_as_uint(f);
  u += 0x7FFFu + ((u >> 16) & 1u);
  return (u16)(u >> 16);
}
__device__ __forceinline__ float b2f(short h) {
  return __uint_as_float(((u32)(u16)h) << 16);
}

// ---------------- weight prep ----------------
__global__ void wprep_kernel(const float* __restrict__ Ws1, const float* __restrict__ Wn1,
                             const float* __restrict__ Ws2, const float* __restrict__ Wn2,
                             const float* __restrict__ Wp, u16* __restrict__ wt) {
  int idx = blockIdx.x * 256 + threadIdx.x;
  if (idx >= 5 * 9216) return;
  int m = idx / 9216, r = idx % 9216;
  int k = r / 96, c = r % 96;
  const float* W = (m == 0) ? Ws1 : (m == 1) ? Wn1 : (m == 2) ? Ws2 : (m == 3) ? Wn2 : Wp;
  wt[m * 9216 + c * 96 + k] = f2b(W[k * 96 + c]);
}

// ---------------- degree histogram ----------------
__global__ void deg_kernel(const int* __restrict__ dst, int* __restrict__ deg) {
  int e = blockIdx.x * blockDim.x + threadIdx.x;
  if (e >= NE) return;
  atomicAdd(&deg[dst[e]], 1);
}

// ---------------- scan phase 1 ----------------
__global__ void scan_sum_kernel(const int* __restrict__ deg, int* __restrict__ bsum) {
  __shared__ int red[256];
  int t = threadIdx.x;
  int base = blockIdx.x * SCAN_CHUNK;
  int s = 0;
  for (int i = t; i < SCAN_CHUNK; i += 256) s += deg[base + i];
  red[t] = s;
  __syncthreads();
  for (int off = 128; off > 0; off >>= 1) {
    if (t < off) red[t] += red[t + off];
    __syncthreads();
  }
  if (t == 0) bsum[blockIdx.x] = red[0];
}

// ---------------- scan phase 2 ----------------
__global__ void scan_bsum_kernel(int* __restrict__ bsum, int* __restrict__ row_start) {
  __shared__ int sm[128];
  int t = threadIdx.x;
  int v = (t < SCAN_BLOCKS) ? bsum[t] : 0;
  sm[t] = v;
  __syncthreads();
  for (int off = 1; off < 128; off <<= 1) {
    int u = 0;
    if (t >= off) u = sm[t - off];
    __syncthreads();
    if (t >= off) sm[t] += u;
    __syncthreads();
  }
  if (t < SCAN_BLOCKS) bsum[t] = sm[t] - v;
  if (t == SCAN_BLOCKS - 1) row_start[NN] = sm[t];
}

// ---------------- scan phase 3 ----------------
__global__ void scan_final_kernel(const int* __restrict__ deg,
                                  const int* __restrict__ bsum,
                                  int* __restrict__ row_start,
                                  int* __restrict__ cursor) {
  __shared__ int sm[256];
  int t = threadIdx.x;
  int base = blockIdx.x * SCAN_CHUNK + t * 4;
  int4 d = {0, 0, 0, 0};
  if (t < 250) d = *reinterpret_cast<const int4*>(deg + base);
  int tot = d.x + d.y + d.z + d.w;
  sm[t] = tot;
  __syncthreads();
  for (int off = 1; off < 256; off <<= 1) {
    int u = 0;
    if (t >= off) u = sm[t - off];
    __syncthreads();
    if (t >= off) sm[t] += u;
    __syncthreads();
  }
  if (t < 250) {
    int run = bsum[blockIdx.x] + sm[t] - tot;
    int4 rs;
    rs.x = run;
    rs.y = run + d.x;
    rs.z = run + d.x + d.y;
    rs.w = run + d.x + d.y + d.z;
    *reinterpret_cast<int4*>(row_start + base) = rs;
    *reinterpret_cast<int4*>(cursor + base) = rs;
  }
}

// ---------------- fill CSR ----------------
__global__ void fill_csr_kernel(const int* __restrict__ src,
                                const int* __restrict__ dst,
                                int* __restrict__ cursor,
                                int* __restrict__ csr) {
  int e = blockIdx.x * blockDim.x + threadIdx.x;
  if (e >= NE) return;
  int pos = atomicAdd(&cursor[dst[e]], 1);
  csr[pos] = src[e];
}

// ---------------- hp = relu(x @ Wp + bp) fused with x->bf16; LDS tile, coalesced writes ----
__global__ __launch_bounds__(512, 2) void hp_gemm_kernel(const float* __restrict__ x,
                                                         const u16* __restrict__ wt,
                                                         const float* __restrict__ bp,
                                                         u16* __restrict__ xh) {
  __shared__ bf16x8 wl[1152];                 // Wp^T
  __shared__ __align__(16) u16 ot[128][200];  // combined x|hp tile, padded (400B rows)
  int t = threadIdx.x;
  const bf16x8* wg = reinterpret_cast<const bf16x8*>(wt + 4 * 9216);
  for (int j = t; j < 1152; j += 512) wl[j] = wg[j];
  __syncthreads();
  int w = t >> 6, lane = t & 63;
  int i = lane & 15, g = lane >> 4;
  int row_base = blockIdx.x * 128 + w * 16;
  int row0 = blockIdx.x * 128;
  int grow_a = row_base + i;
  int lrow = grow_a < NN ? grow_a : NN - 1;
  const float4* xr = reinterpret_cast<const float4*>(x + (size_t)lrow * 96);
  bf16x8 ax[3];
#pragma unroll
  for (int kb = 0; kb < 3; ++kb) {
    float4 p = xr[(kb * 4 + g) * 2];
    float4 q = xr[(kb * 4 + g) * 2 + 1];
    bf16x8 v;
    v[0] = (short)f2b(p.x); v[1] = (short)f2b(p.y); v[2] = (short)f2b(p.z); v[3] = (short)f2b(p.w);
    v[4] = (short)f2b(q.x); v[5] = (short)f2b(q.y); v[6] = (short)f2b(q.z); v[7] = (short)f2b(q.w);
    ax[kb] = v;
    *reinterpret_cast<u16x8*>(&ot[w * 16 + i][(kb * 4 + g) * 8]) = (u16x8)v;  // x half
  }
  for (int nt = 0; nt < 6; ++nt) {
    f32x4 acc = {0.f, 0.f, 0.f, 0.f};
    int bch = (nt * 16 + i) * 12;
#pragma unroll
    for (int kb = 0; kb < 3; ++kb)
      acc = MFMA16(ax[kb], wl[bch + kb * 4 + g], acc, 0, 0, 0);
    int col = nt * 16 + i;
    float bias = bp[col];
#pragma unroll
    for (int r = 0; r < 4; ++r) {
      int lr = w * 16 + g * 4 + r;
      ot[lr][96 + col] = f2b(fmaxf(acc[r] + bias, 0.0f));   // hp half
    }
  }
  __syncthreads();
  // coalesced write-out: 128 rows x 24 u16x8 chunks = 3072, 6 per thread
  bf16x8* dv = reinterpret_cast<bf16x8*>(xh);
#pragma unroll
  for (int c = 0; c < 6; ++c) {
    int ci = t + c * 512;
    int r = ci / 24, cc = ci % 24;
    u16x8 v = *reinterpret_cast<const u16x8*>(&ot[r][cc * 8]);
    dv[(size_t)(row0 + r) * 24 + cc] = (bf16x8)v;
  }
}

// ---------------- fused gather: 32 nodes/block, 8 slots/node, 4-edge pipeline ----------------
__global__ __launch_bounds__(256) void gather_kernel(const u16* __restrict__ xh,
                                                     const int* __restrict__ row_start,
                                                     const int* __restrict__ csr,
                                                     u16* __restrict__ hmbf,
                                                     u16* __restrict__ hxbf) {
  int t = threadIdx.x;
  int node = blockIdx.x * 32 + (t & 31);
  int slot = t >> 5;            // 0..7; sum/max split at wave boundary
  bool isMax = slot >= 4;
  if (node >= NN) return;
  int beg = row_start[node], end = row_start[node + 1];
  int last = (end > beg) ? (end - 1) : 0;
  int cbase = slot * 3;
  const u16x8* XH = reinterpret_cast<const u16x8*>(xh);
  float s0[8], s1[8], s2[8];
  u16x8 m0, m1, m2;
#pragma unroll
  for (int j = 0; j < 8; ++j) {
    s0[j] = 0.f; s1[j] = 0.f; s2[j] = 0.f;
    m0[j] = 0; m1[j] = 0; m2[j] = 0;
  }
  int e = beg;
  int i0 = csr[(beg < end) ? beg : 0];
  int i1 = csr[(beg + 1 <= last) ? beg + 1 : last];
  int i2 = csr[(beg + 2 <= last) ? beg + 2 : last];
  int i3 = csr[(beg + 3 <= last) ? beg + 3 : last];
  for (; e + 4 <= end; e += 4) {
    int p = e + 4;
    int n0 = csr[(p     <= last) ? p     : last];
    int n1 = csr[(p + 1 <= last) ? p + 1 : last];
    int n2 = csr[(p + 2 <= last) ? p + 2 : last];
    int n3 = csr[(p + 3 <= last) ? p + 3 : last];
    size_t b0 = (size_t)i0 * 24 + cbase;
    size_t b1 = (size_t)i1 * 24 + cbase;
    size_t b2 = (size_t)i2 * 24 + cbase;
    size_t b3 = (size_t)i3 * 24 + cbase;
    u16x8 a0 = XH[b0], a1 = XH[b0 + 1], a2 = XH[b0 + 2];
    u16x8 c0 = XH[b1], c1 = XH[b1 + 1], c2 = XH[b1 + 2];
    u16x8 d0 = XH[b2], d1 = XH[b2 + 1], d2 = XH[b2 + 2];
    u16x8 f0 = XH[b3], f1 = XH[b3 + 1], f2 = XH[b3 + 2];
    if (isMax) {
#pragma unroll
      for (int j = 0; j < 8; ++j) {
        u16 p0 = a0[j] > c0[j] ? a0[j] : c0[j];
        u16 q0 = d0[j] > f0[j] ? d0[j] : f0[j];
        u16 r0 = p0 > q0 ? p0 : q0;
        m0[j] = m0[j] > r0 ? m0[j] : r0;
        u16 p1 = a1[j] > c1[j] ? a1[j] : c1[j];
        u16 q1 = d1[j] > f1[j] ? d1[j] : f1[j];
        u16 r1 = p1 > q1 ? p1 : q1;
        m1[j] = m1[j] > r1 ? m1[j] : r1;
        u16 p2 = a2[j] > c2[j] ? a2[j] : c2[j];
        u16 q2 = d2[j] > f2[j] ? d2[j] : f2[j];
        u16 r2 = p2 > q2 ? p2 : q2;
        m2[j] = m2[j] > r2 ? m2[j] : r2;
      }
    } else {
#pragma unroll
      for (int j = 0; j < 8; ++j) {
        s0[j] += (b2f((short)a0[j]) + b2f((short)c0[j])) + (b2f((short)d0[j]) + b2f((short)f0[j]));
        s1[j] += (b2f((short)a1[j]) + b2f((short)c1[j])) + (b2f((short)d1[j]) + b2f((short)f1[j]));
        s2[j] += (b2f((short)a2[j]) + b2f((short)c2[j])) + (b2f((short)d2[j]) + b2f((short)f2[j]));
      }
    }
    i0 = n0; i1 = n1; i2 = n2; i3 = n3;
  }
  int rem = end - e;
#pragma unroll
  for (int k = 0; k < 3; ++k) {
    if (k < rem) {
      int ik = (k == 0) ? i0 : (k == 1) ? i1 : i2;
      size_t b0 = (size_t)ik * 24 + cbase;
      u16x8 a0 = XH[b0], a1 = XH[b0 + 1], a2 = XH[b0 + 2];
      if (isMax) {
#pragma unroll
        for (int j = 0; j < 8; ++j) {
          m0[j] = m0[j] > a0[j] ? m0[j] : a0[j];
          m1[j] = m1[j] > a1[j] ? m1[j] : a1[j];
          m2[j] = m2[j] > a2[j] ? m2[j] : a2[j];
        }
      } else {
#pragma unroll
        for (int j = 0; j < 8; ++j) {
          s0[j] += b2f((short)a0[j]);
          s1[j] += b2f((short)a1[j]);
          s2[j] += b2f((short)a2[j]);
        }
      }
    }
  }
  if (isMax) {
    u16x8* dv = reinterpret_cast<u16x8*>(hxbf);
    size_t ob = (size_t)node * 12 + (slot - 4) * 3;
    dv[ob] = m0; dv[ob + 1] = m1; dv[ob + 2] = m2;
  } else {
    float scl = (end > beg) ? 1.0f / (float)(end - beg) : 0.0f;
    u16x8 w0, w1, w2;
#pragma unroll
    for (int j = 0; j < 8; ++j) {
      w0[j] = f2b(s0[j] * scl);
      w1[j] = f2b(s1[j] * scl);
      w2[j] = f2b(s2[j] * scl);
    }
    u16x8* dv = reinterpret_cast<u16x8*>(hmbf);
    size_t ob = (size_t)node * 12 + slot * 3;
    dv[ob] = w0; dv[ob + 1] = w1; dv[ob + 2] = w2;
  }
}

// ---------------- single fused o-GEMM: o1,o2 bf16 (LDS transpose, coalesced) + BN stats ----
__global__ __launch_bounds__(512, 4) void ogemm_kernel(const u16* __restrict__ xh,
                                                       u16* __restrict__ hmbf,
                                                       u16* __restrict__ hxbf,
                                                       const u16* __restrict__ wt,
                                                       float* __restrict__ stats) {
  __shared__ bf16x8 wl[2304];                 // two matrices at a time
  __shared__ float smst[384];
  __shared__ __align__(16) u16 ot[128][104];  // o tile, padded rows
  int t = threadIdx.x;
  const bf16x8* wg = reinterpret_cast<const bf16x8*>(wt);
  for (int j = t; j < 2304; j += 512) wl[j] = wg[j];          // Ws1, Wn1
  for (int j = t; j < 384; j += 512) smst[j] = 0.f;
  __syncthreads();
  int w = t >> 6, lane = t & 63;
  int i = lane & 15, g = lane >> 4;
  int row_base = blockIdx.x * 128 + w * 16;
  int row0 = blockIdx.x * 128;
  size_t arowx = (size_t)(row_base + i) * 24;
  size_t arowh = (size_t)(row_base + i) * 12;
  const bf16x8* X = reinterpret_cast<const bf16x8*>(xh);
  const bf16x8* M = reinterpret_cast<const bf16x8*>(hmbf);
  const bf16x8* H = reinterpret_cast<const bf16x8*>(hxbf);
  bf16x8 ax0 = X[arowx + g], ax1 = X[arowx + 4 + g], ax2 = X[arowx + 8 + g];
  // ---- phase 1: o1 ----
  {
    bf16x8 am0 = M[arowh + g], am1 = M[arowh + 4 + g], am2 = M[arowh + 8 + g];
#pragma unroll
    for (int nt = 0; nt < 6; ++nt) {
      f32x4 a1 = {0.f, 0.f, 0.f, 0.f};
      int bch = (nt * 16 + i) * 12 + g;
      a1 = MFMA16(ax0, wl[bch], a1, 0, 0, 0);
      a1 = MFMA16(ax1, wl[bch + 4], a1, 0, 0, 0);
      a1 = MFMA16(ax2, wl[bch + 8], a1, 0, 0, 0);
      a1 = MFMA16(am0, wl[1152 + bch], a1, 0, 0, 0);
      a1 = MFMA16(am1, wl[1152 + bch + 4], a1, 0, 0, 0);
      a1 = MFMA16(am2, wl[1152 + bch + 8], a1, 0, 0, 0);
      int col = nt * 16 + i;
      float s1 = 0, q1 = 0;
#pragma unroll
      for (int r = 0; r < 4; ++r) {
        int lrow = w * 16 + g * 4 + r;
        ot[lrow][col] = f2b(a1[r]);
        if (row0 + lrow < NN) { float v = a1[r]; s1 += v; q1 += v * v; }
      }
      s1 += __shfl_xor(s1, 16); q1 += __shfl_xor(q1, 16);
      s1 += __shfl_xor(s1, 32); q1 += __shfl_xor(q1, 32);
      if (g == 0) {
        atomicAdd(&smst[col], s1);
        atomicAdd(&smst[96 + col], q1);
      }
    }
  }
  __syncthreads();
  {
    u16x8* dv = reinterpret_cast<u16x8*>(hmbf);
#pragma unroll
    for (int c = 0; c < 3; ++c) {
      int ci = t + c * 512;
      int r = ci / 12, cc = ci % 12;
      u16x8 v = *reinterpret_cast<const u16x8*>(&ot[r][cc * 8]);
      dv[(size_t)(row0 + r) * 12 + cc] = v;
    }
    for (int j = t; j < 2304; j += 512) wl[j] = wg[2304 + j];
  }
  __syncthreads();
  // ---- phase 2: o2 ----
  {
    bf16x8 ah0 = H[arowh + g], ah1 = H[arowh + 4 + g], ah2 = H[arowh + 8 + g];
#pragma unroll
    for (int nt = 0; nt < 6; ++nt) {
      f32x4 a2 = {0.f, 0.f, 0.f, 0.f};
      int bch = (nt * 16 + i) * 12 + g;
      a2 = MFMA16(ax0, wl[bch], a2, 0, 0, 0);
      a2 = MFMA16(ax1, wl[bch + 4], a2, 0, 0, 0);
      a2 = MFMA16(ax2, wl[bch + 8], a2, 0, 0, 0);
      a2 = MFMA16(ah0, wl[1152 + bch], a2, 0, 0, 0);
      a2 = MFMA16(ah1, wl[1152 + bch + 4], a2, 0, 0, 0);
      a2 = MFMA16(ah2, wl[1152 + bch + 8], a2, 0, 0, 0);
      int col = nt * 16 + i;
      float s2 = 0, q2 = 0;
#pragma unroll
      for (int r = 0; r < 4; ++r) {
        int lrow = w * 16 + g * 4 + r;
        ot[lrow][col] = f2b(a2[r]);
        if (row0 + lrow < NN) { float v = a2[r]; s2 += v; q2 += v * v; }
      }
      s2 += __shfl_xor(s2, 16); q2 += __shfl_xor(q2, 16);
      s2 += __shfl_xor(s2, 32); q2 += __shfl_xor(q2, 32);
      if (g == 0) {
        atomicAdd(&smst[192 + col], s2);
        atomicAdd(&smst[288 + col], q2);
      }
    }
  }
  __syncthreads();
  {
    u16x8* dv = reinterpret_cast<u16x8*>(hxbf);
#pragma unroll
    for (int c = 0; c < 3; ++c) {
      int ci = t + c * 512;
      int r = ci / 12, cc = ci % 12;
      u16x8 v = *reinterpret_cast<const u16x8*>(&ot[r][cc * 8]);
      dv[(size_t)(row0 + r) * 12 + cc] = v;
    }
  }
  for (int j = t; j < 384; j += 512) atomicAdd(&stats[j], smst[j]);
}

// ---------------- out = leaky(bn1(o1)+bn2(o2)), streaming, inline BN-fold ----------------
__global__ __launch_bounds__(256) void final_kernel(const u16* __restrict__ o1,
                                                    const u16* __restrict__ o2,
                                                    const float* __restrict__ stats,
                                                    const float* __restrict__ g1,
                                                    const float* __restrict__ beta1,
                                                    const float* __restrict__ g2,
                                                    const float* __restrict__ beta2,
                                                    float* __restrict__ out) {
  __shared__ float pl[384];
  int t = threadIdx.x;
  if (t < 96) {
    const float inv_n = 1.0f / NN;
    float mu1 = stats[t] * inv_n;
    float var1 = fmaxf(stats[96 + t] * inv_n - mu1 * mu1, 0.0f);
    float a1 = g1[t] * rsqrtf(var1 + 1e-5f);
    pl[t] = a1;
    pl[96 + t] = beta1[t] - a1 * mu1;
    float mu2 = stats[192 + t] * inv_n;
    float var2 = fmaxf(stats[288 + t] * inv_n - mu2 * mu2, 0.0f);
    float a2 = g2[t] * rsqrtf(var2 + 1e-5f);
    pl[192 + t] = a2;
    pl[288 + t] = beta2[t] - a2 * mu2;
  }
  __syncthreads();
  int idx = blockIdx.x * 256 + t;   // one bf16x8 chunk
  if (idx >= NN * 12) return;
  int c8 = idx % 12;
  bf16x8 v1 = reinterpret_cast<const bf16x8*>(o1)[idx];
  bf16x8 v2 = reinterpret_cast<const bf16x8*>(o2)[idx];
  float o[8];
#pragma unroll
  for (int j = 0; j < 8; ++j) {
    int col = c8 * 8 + j;
    float v = pl[col] * b2f((short)v1[j]) + pl[96 + col]
            + pl[192 + col] * b2f((short)v2[j]) + pl[288 + col];
    o[j] = v > 0.f ? v : 0.01f * v;
  }
  float4* ov = reinterpret_cast<float4*>(out);
  float4 lo = {o[0], o[1], o[2], o[3]}, hi = {o[4], o[5], o[6], o[7]};
  ov[idx * 2] = lo;
  ov[idx * 2 + 1] = hi;
}

extern "C" void kernel_launch(void* const* d_in, const int* in_sizes, int n_in,
                              void* d_out, int out_size, void* d_ws, size_t ws_size,
                              hipStream_t stream) {
  const float* x       = (const float*)d_in[0];
  const int*   ei      = (const int*)d_in[1];
  const float* W_self1 = (const float*)d_in[2];
  const float* W_neigh1= (const float*)d_in[3];
  const float* W_pool  = (const float*)d_in[4];
  const float* b_pool  = (const float*)d_in[5];
  const float* W_self2 = (const float*)d_in[6];
  const float* W_neigh2= (const float*)d_in[7];
  const float* g1      = (const float*)d_in[8];
  const float* beta1   = (const float*)d_in[9];
  const float* g2      = (const float*)d_in[10];
  const float* beta2   = (const float*)d_in[11];
  float* out = (float*)d_out;

  float* ws = (float*)d_ws;
  int*   deg       = (int*)(ws + OFF_DEG);
  int*   row_start = (int*)(ws + OFF_ROWSTART);
  int*   cursor    = (int*)(ws + OFF_CURSOR);
  int*   bsum      = (int*)(ws + OFF_BSUM);
  float* stats     = ws + OFF_STATS;
  u16*   wt        = (u16*)(ws + OFF_WT);
  int*   csr       = (int*)(ws + OFF_CSR);
  u16*   xh        = (u16*)(ws + OFF_XH);
  u16*   hmbf      = (u16*)(ws + OFF_HMBF);
  u16*   hxbf      = (u16*)(ws + OFF_HXBF);

  const int* src = ei;
  const int* dst = ei + NE;

  hipMemsetAsync(deg, 0, NN * sizeof(int), stream);
  hipMemsetAsync(stats, 0, 384 * sizeof(float), stream);

  wprep_kernel<<<(5 * 9216 + 255) / 256, 256, 0, stream>>>(W_self1, W_neigh1, W_self2,
                                                           W_neigh2, W_pool, wt);

  deg_kernel<<<(NE + 255) / 256, 256, 0, stream>>>(dst, deg);
  scan_sum_kernel<<<SCAN_BLOCKS, 256, 0, stream>>>(deg, bsum);
  scan_bsum_kernel<<<1, 128, 0, stream>>>(bsum, row_start);
  scan_final_kernel<<<SCAN_BLOCKS, 256, 0, stream>>>(deg, bsum, row_start, cursor);
  fill_csr_kernel<<<(NE + 255) / 256, 256, 0, stream>>>(src, dst, cursor, csr);

  hp_gemm_kernel<<<GBLK, 512, 0, stream>>>(x, wt, b_pool, xh);

  gather_kernel<<<(NN + 31) / 32, 256, 0, stream>>>(xh, row_start, csr, hmbf, hxbf);

  ogemm_kernel<<<GBLK, 512, 0, stream>>>(xh, hmbf, hxbf, wt, stats);
  final_kernel<<<(NN * 12 + 255) / 256, 256, 0, stream>>>(hmbf, hxbf, stats,
                                                          g1, beta1, g2, beta2, out);
}

// Round 16
// 247.672 us; speedup vs baseline: 2.5575x; 1.0330x over previous
//
#include <hip/hip_runtime.h>

#define NN 100000
#define NE 800000
#define DD 96
#define NROWPAD 100096            // 782 * 128
#define GBLK 782                  // GEMM blocks (128 rows each)
#define SCAN_BLOCKS 100
#define SCAN_CHUNK 1000

typedef __attribute__((ext_vector_type(8))) short bf16x8;
typedef __attribute__((ext_vector_type(8))) unsigned short u16x8;
typedef __attribute__((ext_vector_type(4))) float f32x4;
typedef unsigned short u16;
typedef unsigned int u32;

#define MFMA16 __builtin_amdgcn_mfma_f32_16x16x32_bf16

// workspace layout (4-byte element offsets)
#define OFF_DEG      0u          // NN ints
#define OFF_ROWSTART 100000u     // NN+1 ints
#define OFF_CURSOR   200004u     // NN ints
#define OFF_BSUM     300004u     // 128 ints
#define OFF_STATS    302180u     // 384 floats
#define OFF_WT       302948u     // 5*9216 bf16 = 23040 floats
#define OFF_CSR      325988u     // NE ints
#define OFF_XH       1125988u    // NROWPAD*96 floats (combined x|hp bf16 rows, 384B)
#define OFF_HMBF     10735204u   // NROWPAD*48 floats -> becomes o1 (bf16)
#define OFF_HXBF     15539812u   // NROWPAD*48 floats -> becomes o2 (bf16)

__device__ __forceinline__ u16 f2b(float f) {
  u32 u = __float_as_uint(f);
  u += 0x7FFFu + ((u >> 16) & 1u);
  return (u16)(u >> 16);
}
__device__ __forceinline__ float b2f(short h) {
  return __uint_as_float(((u32)(u16)h) << 16);
}

// ---------------- weight prep ----------------
__global__ void wprep_kernel(const float* __restrict__ Ws1, const float* __restrict__ Wn1,
                             const float* __restrict__ Ws2, const float* __restrict__ Wn2,
                             const float* __restrict__ Wp, u16* __restrict__ wt) {
  int idx = blockIdx.x * 256 + threadIdx.x;
  if (idx >= 5 * 9216) return;
  int m = idx / 9216, r = idx % 9216;
  int k = r / 96, c = r % 96;
  const float* W = (m == 0) ? Ws1 : (m == 1) ? Wn1 : (m == 2) ? Ws2 : (m == 3) ? Wn2 : Wp;
  wt[m * 9216 + c * 96 + k] = f2b(W[k * 96 + c]);
}

// ---------------- degree histogram ----------------
__global__ void deg_kernel(const int* __restrict__ dst, int* __restrict__ deg) {
  int e = blockIdx.x * blockDim.x + threadIdx.x;
  if (e >= NE) return;
  atomicAdd(&deg[dst[e]], 1);
}

// ---------------- scan phase 1: per-block sums ----------------
__global__ void scan_sum_kernel(const int* __restrict__ deg, int* __restrict__ bsum) {
  __shared__ int red[256];
  int t = threadIdx.x;
  int base = blockIdx.x * SCAN_CHUNK;
  int s = 0;
  for (int i = t; i < SCAN_CHUNK; i += 256) s += deg[base + i];
  red[t] = s;
  __syncthreads();
  for (int off = 128; off > 0; off >>= 1) {
    if (t < off) red[t] += red[t + off];
    __syncthreads();
  }
  if (t == 0) bsum[blockIdx.x] = red[0];
}

// ---------------- scan phase 2: local scan + inline bsum scan ----------------
__global__ void scan_final_kernel(const int* __restrict__ deg,
                                  const int* __restrict__ bsum,
                                  int* __restrict__ row_start,
                                  int* __restrict__ cursor) {
  __shared__ int sb[128];
  __shared__ int sm[256];
  __shared__ int sbase;
  int t = threadIdx.x;
  if (t < 128) sb[t] = (t < SCAN_BLOCKS) ? bsum[t] : 0;
  __syncthreads();
  for (int off = 1; off < 128; off <<= 1) {
    int u = 0;
    if (t < 128 && t >= off) u = sb[t - off];
    __syncthreads();
    if (t < 128 && t >= off) sb[t] += u;
    __syncthreads();
  }
  if (t == 0) {
    sbase = (blockIdx.x == 0) ? 0 : sb[blockIdx.x - 1];
    if (blockIdx.x == 0) row_start[NN] = sb[SCAN_BLOCKS - 1];
  }
  int base = blockIdx.x * SCAN_CHUNK + t * 4;
  int4 d = {0, 0, 0, 0};
  if (t < 250) d = *reinterpret_cast<const int4*>(deg + base);
  int tot = d.x + d.y + d.z + d.w;
  sm[t] = tot;
  __syncthreads();
  for (int off = 1; off < 256; off <<= 1) {
    int u = 0;
    if (t >= off) u = sm[t - off];
    __syncthreads();
    if (t >= off) sm[t] += u;
    __syncthreads();
  }
  if (t < 250) {
    int run = sbase + sm[t] - tot;
    int4 rs;
    rs.x = run;
    rs.y = run + d.x;
    rs.z = run + d.x + d.y;
    rs.w = run + d.x + d.y + d.z;
    *reinterpret_cast<int4*>(row_start + base) = rs;
    *reinterpret_cast<int4*>(cursor + base) = rs;
  }
}

// ---------------- fill CSR ----------------
__global__ void fill_csr_kernel(const int* __restrict__ src,
                                const int* __restrict__ dst,
                                int* __restrict__ cursor,
                                int* __restrict__ csr) {
  int e = blockIdx.x * blockDim.x + threadIdx.x;
  if (e >= NE) return;
  int pos = atomicAdd(&cursor[dst[e]], 1);
  csr[pos] = src[e];
}

// ---------------- hp = relu(x @ Wp + bp) fused with x->bf16; LDS tile, coalesced writes ----
__global__ __launch_bounds__(512, 2) void hp_gemm_kernel(const float* __restrict__ x,
                                                         const u16* __restrict__ wt,
                                                         const float* __restrict__ bp,
                                                         u16* __restrict__ xh) {
  __shared__ bf16x8 wl[1152];                 // Wp^T
  __shared__ __align__(16) u16 ot[128][200];  // combined x|hp tile, padded (400B rows)
  int t = threadIdx.x;
  const bf16x8* wg = reinterpret_cast<const bf16x8*>(wt + 4 * 9216);
  for (int j = t; j < 1152; j += 512) wl[j] = wg[j];
  __syncthreads();
  int w = t >> 6, lane = t & 63;
  int i = lane & 15, g = lane >> 4;
  int row_base = blockIdx.x * 128 + w * 16;
  int row0 = blockIdx.x * 128;
  int grow_a = row_base + i;
  int lrow = grow_a < NN ? grow_a : NN - 1;
  const float4* xr = reinterpret_cast<const float4*>(x + (size_t)lrow * 96);
  bf16x8 ax[3];
#pragma unroll
  for (int kb = 0; kb < 3; ++kb) {
    float4 p = xr[(kb * 4 + g) * 2];
    float4 q = xr[(kb * 4 + g) * 2 + 1];
    bf16x8 v;
    v[0] = (short)f2b(p.x); v[1] = (short)f2b(p.y); v[2] = (short)f2b(p.z); v[3] = (short)f2b(p.w);
    v[4] = (short)f2b(q.x); v[5] = (short)f2b(q.y); v[6] = (short)f2b(q.z); v[7] = (short)f2b(q.w);
    ax[kb] = v;
    *reinterpret_cast<u16x8*>(&ot[w * 16 + i][(kb * 4 + g) * 8]) = (u16x8)v;  // x half
  }
  for (int nt = 0; nt < 6; ++nt) {
    f32x4 acc = {0.f, 0.f, 0.f, 0.f};
    int bch = (nt * 16 + i) * 12;
#pragma unroll
    for (int kb = 0; kb < 3; ++kb)
      acc = MFMA16(ax[kb], wl[bch + kb * 4 + g], acc, 0, 0, 0);
    int col = nt * 16 + i;
    float bias = bp[col];
#pragma unroll
    for (int r = 0; r < 4; ++r) {
      int lr = w * 16 + g * 4 + r;
      ot[lr][96 + col] = f2b(fmaxf(acc[r] + bias, 0.0f));   // hp half
    }
  }
  __syncthreads();
  // coalesced write-out: 128 rows x 24 u16x8 chunks = 3072, 6 per thread
  bf16x8* dv = reinterpret_cast<bf16x8*>(xh);
#pragma unroll
  for (int c = 0; c < 6; ++c) {
    int ci = t + c * 512;
    int r = ci / 24, cc = ci % 24;
    u16x8 v = *reinterpret_cast<const u16x8*>(&ot[r][cc * 8]);
    dv[(size_t)(row0 + r) * 24 + cc] = (bf16x8)v;
  }
}

// ---------------- fused gather: 16 nodes/block (128 thr), 8 slots/node, 4-edge pipeline ----
__global__ __launch_bounds__(128) void gather_kernel(const u16* __restrict__ xh,
                                                     const int* __restrict__ row_start,
                                                     const int* __restrict__ csr,
                                                     u16* __restrict__ hmbf,
                                                     u16* __restrict__ hxbf) {
  int t = threadIdx.x;
  int node = blockIdx.x * 16 + (t & 15);    // NN/16 = 6250 exact
  int slot = t >> 4;            // 0..7; sum (0-3) / max (4-7) split at wave boundary
  bool isMax = slot >= 4;
  int beg = row_start[node], end = row_start[node + 1];
  int last = (end > beg) ? (end - 1) : 0;
  int cbase = slot * 3;
  const u16x8* XH = reinterpret_cast<const u16x8*>(xh);
  float s0[8], s1[8], s2[8];
  u16x8 m0, m1, m2;
#pragma unroll
  for (int j = 0; j < 8; ++j) {
    s0[j] = 0.f; s1[j] = 0.f; s2[j] = 0.f;
    m0[j] = 0; m1[j] = 0; m2[j] = 0;
  }
  int e = beg;
  int i0 = csr[(beg < end) ? beg : 0];
  int i1 = csr[(beg + 1 <= last) ? beg + 1 : last];
  int i2 = csr[(beg + 2 <= last) ? beg + 2 : last];
  int i3 = csr[(beg + 3 <= last) ? beg + 3 : last];
  for (; e + 4 <= end; e += 4) {
    int p = e + 4;
    int n0 = csr[(p     <= last) ? p     : last];
    int n1 = csr[(p + 1 <= last) ? p + 1 : last];
    int n2 = csr[(p + 2 <= last) ? p + 2 : last];
    int n3 = csr[(p + 3 <= last) ? p + 3 : last];
    size_t b0 = (size_t)i0 * 24 + cbase;
    size_t b1 = (size_t)i1 * 24 + cbase;
    size_t b2 = (size_t)i2 * 24 + cbase;
    size_t b3 = (size_t)i3 * 24 + cbase;
    u16x8 a0 = XH[b0], a1 = XH[b0 + 1], a2 = XH[b0 + 2];
    u16x8 c0 = XH[b1], c1 = XH[b1 + 1], c2 = XH[b1 + 2];
    u16x8 d0 = XH[b2], d1 = XH[b2 + 1], d2 = XH[b2 + 2];
    u16x8 f0 = XH[b3], f1 = XH[b3 + 1], f2 = XH[b3 + 2];
    if (isMax) {
#pragma unroll
      for (int j = 0; j < 8; ++j) {
        u16 p0 = a0[j] > c0[j] ? a0[j] : c0[j];
        u16 q0 = d0[j] > f0[j] ? d0[j] : f0[j];
        u16 r0 = p0 > q0 ? p0 : q0;
        m0[j] = m0[j] > r0 ? m0[j] : r0;
        u16 p1 = a1[j] > c1[j] ? a1[j] : c1[j];
        u16 q1 = d1[j] > f1[j] ? d1[j] : f1[j];
        u16 r1 = p1 > q1 ? p1 : q1;
        m1[j] = m1[j] > r1 ? m1[j] : r1;
        u16 p2 = a2[j] > c2[j] ? a2[j] : c2[j];
        u16 q2 = d2[j] > f2[j] ? d2[j] : f2[j];
        u16 r2 = p2 > q2 ? p2 : q2;
        m2[j] = m2[j] > r2 ? m2[j] : r2;
      }
    } else {
#pragma unroll
      for (int j = 0; j < 8; ++j) {
        s0[j] += (b2f((short)a0[j]) + b2f((short)c0[j])) + (b2f((short)d0[j]) + b2f((short)f0[j]));
        s1[j] += (b2f((short)a1[j]) + b2f((short)c1[j])) + (b2f((short)d1[j]) + b2f((short)f1[j]));
        s2[j] += (b2f((short)a2[j]) + b2f((short)c2[j])) + (b2f((short)d2[j]) + b2f((short)f2[j]));
      }
    }
    i0 = n0; i1 = n1; i2 = n2; i3 = n3;
  }
  int rem = end - e;
#pragma unroll
  for (int k = 0; k < 3; ++k) {
    if (k < rem) {
      int ik = (k == 0) ? i0 : (k == 1) ? i1 : i2;
      size_t b0 = (size_t)ik * 24 + cbase;
      u16x8 a0 = XH[b0], a1 = XH[b0 + 1], a2 = XH[b0 + 2];
      if (isMax) {
#pragma unroll
        for (int j = 0; j < 8; ++j) {
          m0[j] = m0[j] > a0[j] ? m0[j] : a0[j];
          m1[j] = m1[j] > a1[j] ? m1[j] : a1[j];
          m2[j] = m2[j] > a2[j] ? m2[j] : a2[j];
        }
      } else {
#pragma unroll
        for (int j = 0; j < 8; ++j) {
          s0[j] += b2f((short)a0[j]);
          s1[j] += b2f((short)a1[j]);
          s2[j] += b2f((short)a2[j]);
        }
      }
    }
  }
  if (isMax) {
    u16x8* dv = reinterpret_cast<u16x8*>(hxbf);
    size_t ob = (size_t)node * 12 + (slot - 4) * 3;
    dv[ob] = m0; dv[ob + 1] = m1; dv[ob + 2] = m2;
  } else {
    float scl = (end > beg) ? 1.0f / (float)(end - beg) : 0.0f;
    u16x8 w0, w1, w2;
#pragma unroll
    for (int j = 0; j < 8; ++j) {
      w0[j] = f2b(s0[j] * scl);
      w1[j] = f2b(s1[j] * scl);
      w2[j] = f2b(s2[j] * scl);
    }
    u16x8* dv = reinterpret_cast<u16x8*>(hmbf);
    size_t ob = (size_t)node * 12 + slot * 3;
    dv[ob] = w0; dv[ob + 1] = w1; dv[ob + 2] = w2;
  }
}

// ---------------- single fused o-GEMM: o1,o2 bf16 (LDS transpose, coalesced) + BN stats ----
__global__ __launch_bounds__(512, 4) void ogemm_kernel(const u16* __restrict__ xh,
                                                       u16* __restrict__ hmbf,
                                                       u16* __restrict__ hxbf,
                                                       const u16* __restrict__ wt,
                                                       float* __restrict__ stats) {
  __shared__ bf16x8 wl[2304];                 // two matrices at a time
  __shared__ float smst[384];
  __shared__ __align__(16) u16 ot[128][104];  // o tile, padded rows
  int t = threadIdx.x;
  const bf16x8* wg = reinterpret_cast<const bf16x8*>(wt);
  for (int j = t; j < 2304; j += 512) wl[j] = wg[j];          // Ws1, Wn1
  for (int j = t; j < 384; j += 512) smst[j] = 0.f;
  __syncthreads();
  int w = t >> 6, lane = t & 63;
  int i = lane & 15, g = lane >> 4;
  int row_base = blockIdx.x * 128 + w * 16;
  int row0 = blockIdx.x * 128;
  size_t arowx = (size_t)(row_base + i) * 24;
  size_t arowh = (size_t)(row_base + i) * 12;
  const bf16x8* X = reinterpret_cast<const bf16x8*>(xh);
  const bf16x8* M = reinterpret_cast<const bf16x8*>(hmbf);
  const bf16x8* H = reinterpret_cast<const bf16x8*>(hxbf);
  bf16x8 ax0 = X[arowx + g], ax1 = X[arowx + 4 + g], ax2 = X[arowx + 8 + g];
  // ---- phase 1: o1 ----
  {
    bf16x8 am0 = M[arowh + g], am1 = M[arowh + 4 + g], am2 = M[arowh + 8 + g];
#pragma unroll
    for (int nt = 0; nt < 6; ++nt) {
      f32x4 a1 = {0.f, 0.f, 0.f, 0.f};
      int bch = (nt * 16 + i) * 12 + g;
      a1 = MFMA16(ax0, wl[bch], a1, 0, 0, 0);
      a1 = MFMA16(ax1, wl[bch + 4], a1, 0, 0, 0);
      a1 = MFMA16(ax2, wl[bch + 8], a1, 0, 0, 0);
      a1 = MFMA16(am0, wl[1152 + bch], a1, 0, 0, 0);
      a1 = MFMA16(am1, wl[1152 + bch + 4], a1, 0, 0, 0);
      a1 = MFMA16(am2, wl[1152 + bch + 8], a1, 0, 0, 0);
      int col = nt * 16 + i;
      float s1 = 0, q1 = 0;
#pragma unroll
      for (int r = 0; r < 4; ++r) {
        int lrow = w * 16 + g * 4 + r;
        ot[lrow][col] = f2b(a1[r]);
        if (row0 + lrow < NN) { float v = a1[r]; s1 += v; q1 += v * v; }
      }
      s1 += __shfl_xor(s1, 16); q1 += __shfl_xor(q1, 16);
      s1 += __shfl_xor(s1, 32); q1 += __shfl_xor(q1, 32);
      if (g == 0) {
        atomicAdd(&smst[col], s1);
        atomicAdd(&smst[96 + col], q1);
      }
    }
  }
  __syncthreads();
  {
    u16x8* dv = reinterpret_cast<u16x8*>(hmbf);
#pragma unroll
    for (int c = 0; c < 3; ++c) {
      int ci = t + c * 512;
      int r = ci / 12, cc = ci % 12;
      u16x8 v = *reinterpret_cast<const u16x8*>(&ot[r][cc * 8]);
      dv[(size_t)(row0 + r) * 12 + cc] = v;
    }
    for (int j = t; j < 2304; j += 512) wl[j] = wg[2304 + j];
  }
  __syncthreads();
  // ---- phase 2: o2 ----
  {
    bf16x8 ah0 = H[arowh + g], ah1 = H[arowh + 4 + g], ah2 = H[arowh + 8 + g];
#pragma unroll
    for (int nt = 0; nt < 6; ++nt) {
      f32x4 a2 = {0.f, 0.f, 0.f, 0.f};
      int bch = (nt * 16 + i) * 12 + g;
      a2 = MFMA16(ax0, wl[bch], a2, 0, 0, 0);
      a2 = MFMA16(ax1, wl[bch + 4], a2, 0, 0, 0);
      a2 = MFMA16(ax2, wl[bch + 8], a2, 0, 0, 0);
      a2 = MFMA16(ah0, wl[1152 + bch], a2, 0, 0, 0);
      a2 = MFMA16(ah1, wl[1152 + bch + 4], a2, 0, 0, 0);
      a2 = MFMA16(ah2, wl[1152 + bch + 8], a2, 0, 0, 0);
      int col = nt * 16 + i;
      float s2 = 0, q2 = 0;
#pragma unroll
      for (int r = 0; r < 4; ++r) {
        int lrow = w * 16 + g * 4 + r;
        ot[lrow][col] = f2b(a2[r]);
        if (row0 + lrow < NN) { float v = a2[r]; s2 += v; q2 += v * v; }
      }
      s2 += __shfl_xor(s2, 16); q2 += __shfl_xor(q2, 16);
      s2 += __shfl_xor(s2, 32); q2 += __shfl_xor(q2, 32);
      if (g == 0) {
        atomicAdd(&smst[192 + col], s2);
        atomicAdd(&smst[288 + col], q2);
      }
    }
  }
  __syncthreads();
  {
    u16x8* dv = reinterpret_cast<u16x8*>(hxbf);
#pragma unroll
    for (int c = 0; c < 3; ++c) {
      int ci = t + c * 512;
      int r = ci / 12, cc = ci % 12;
      u16x8 v = *reinterpret_cast<const u16x8*>(&ot[r][cc * 8]);
      dv[(size_t)(row0 + r) * 12 + cc] = v;
    }
  }
  for (int j = t; j < 384; j += 512) atomicAdd(&stats[j], smst[j]);
}

// ---------------- out = leaky(bn1(o1)+bn2(o2)), streaming, inline BN-fold ----------------
__global__ __launch_bounds__(512) void final_kernel(const u16* __restrict__ o1,
                                                    const u16* __restrict__ o2,
                                                    const float* __restrict__ stats,
                                                    const float* __restrict__ g1,
                                                    const float* __restrict__ beta1,
                                                    const float* __restrict__ g2,
                                                    const float* __restrict__ beta2,
                                                    float* __restrict__ out) {
  __shared__ float pl[384];
  int t = threadIdx.x;
  if (t < 96) {
    const float inv_n = 1.0f / NN;
    float mu1 = stats[t] * inv_n;
    float var1 = fmaxf(stats[96 + t] * inv_n - mu1 * mu1, 0.0f);
    float a1 = g1[t] * rsqrtf(var1 + 1e-5f);
    pl[t] = a1;
    pl[96 + t] = beta1[t] - a1 * mu1;
    float mu2 = stats[192 + t] * inv_n;
    float var2 = fmaxf(stats[288 + t] * inv_n - mu2 * mu2, 0.0f);
    float a2 = g2[t] * rsqrtf(var2 + 1e-5f);
    pl[192 + t] = a2;
    pl[288 + t] = beta2[t] - a2 * mu2;
  }
  __syncthreads();
#pragma unroll
  for (int c = 0; c < 2; ++c) {
    int idx = blockIdx.x * 1024 + c * 512 + t;   // one bf16x8 chunk
    if (idx >= NN * 12) continue;
    int c8 = idx % 12;
    bf16x8 v1 = reinterpret_cast<const bf16x8*>(o1)[idx];
    bf16x8 v2 = reinterpret_cast<const bf16x8*>(o2)[idx];
    float o[8];
#pragma unroll
    for (int j = 0; j < 8; ++j) {
      int col = c8 * 8 + j;
      float v = pl[col] * b2f((short)v1[j]) + pl[96 + col]
              + pl[192 + col] * b2f((short)v2[j]) + pl[288 + col];
      o[j] = v > 0.f ? v : 0.01f * v;
    }
    float4* ov = reinterpret_cast<float4*>(out);
    float4 lo = {o[0], o[1], o[2], o[3]}, hi = {o[4], o[5], o[6], o[7]};
    ov[idx * 2] = lo;
    ov[idx * 2 + 1] = hi;
  }
}

extern "C" void kernel_launch(void* const* d_in, const int* in_sizes, int n_in,
                              void* d_out, int out_size, void* d_ws, size_t ws_size,
                              hipStream_t stream) {
  const float* x       = (const float*)d_in[0];
  const int*   ei      = (const int*)d_in[1];
  const float* W_self1 = (const float*)d_in[2];
  const float* W_neigh1= (const float*)d_in[3];
  const float* W_pool  = (const float*)d_in[4];
  const float* b_pool  = (const float*)d_in[5];
  const float* W_self2 = (const float*)d_in[6];
  const float* W_neigh2= (const float*)d_in[7];
  const float* g1      = (const float*)d_in[8];
  const float* beta1   = (const float*)d_in[9];
  const float* g2      = (const float*)d_in[10];
  const float* beta2   = (const float*)d_in[11];
  float* out = (float*)d_out;

  float* ws = (float*)d_ws;
  int*   deg       = (int*)(ws + OFF_DEG);
  int*   row_start = (int*)(ws + OFF_ROWSTART);
  int*   cursor    = (int*)(ws + OFF_CURSOR);
  int*   bsum      = (int*)(ws + OFF_BSUM);
  float* stats     = ws + OFF_STATS;
  u16*   wt        = (u16*)(ws + OFF_WT);
  int*   csr       = (int*)(ws + OFF_CSR);
  u16*   xh        = (u16*)(ws + OFF_XH);
  u16*   hmbf      = (u16*)(ws + OFF_HMBF);
  u16*   hxbf      = (u16*)(ws + OFF_HXBF);

  const int* src = ei;
  const int* dst = ei + NE;

  hipMemsetAsync(deg, 0, NN * sizeof(int), stream);
  hipMemsetAsync(stats, 0, 384 * sizeof(float), stream);

  wprep_kernel<<<(5 * 9216 + 255) / 256, 256, 0, stream>>>(W_self1, W_neigh1, W_self2,
                                                           W_neigh2, W_pool, wt);

  deg_kernel<<<(NE + 255) / 256, 256, 0, stream>>>(dst, deg);
  scan_sum_kernel<<<SCAN_BLOCKS, 256, 0, stream>>>(deg, bsum);
  scan_final_kernel<<<SCAN_BLOCKS, 256, 0, stream>>>(deg, bsum, row_start, cursor);
  fill_csr_kernel<<<(NE + 255) / 256, 256, 0, stream>>>(src, dst, cursor, csr);

  hp_gemm_kernel<<<GBLK, 512, 0, stream>>>(x, wt, b_pool, xh);

  gather_kernel<<<NN / 16, 128, 0, stream>>>(xh, row_start, csr, hmbf, hxbf);

  ogemm_kernel<<<GBLK, 512, 0, stream>>>(xh, hmbf, hxbf, wt, stats);
  final_kernel<<<(NN * 12 + 1023) / 1024, 512, 0, stream>>>(hmbf, hxbf, stats,
                                                            g1, beta1, g2, beta2, out);
}